// Round 1
// baseline (551.092 us; speedup 1.0000x reference)
//
#include <hip/hip_runtime.h>

// Problem constants
#define S_LEN   1024
#define NH      16
#define HD      64
#define BATCHN  8
#define DMODEL  1024
#define HALF_W  16          // window//2

typedef __attribute__((ext_vector_type(8))) short bf16x8;   // 8 bf16 = 4 VGPRs
typedef __attribute__((ext_vector_type(4))) float f32x4;

__device__ __forceinline__ unsigned short f2bf(float f) {
  unsigned u = __builtin_bit_cast(unsigned, f);
  u += 0x7fffu + ((u >> 16) & 1u);          // round-to-nearest-even
  return (unsigned short)(u >> 16);
}
__device__ __forceinline__ float bf2f(unsigned short h) {
  return __builtin_bit_cast(float, ((unsigned)h) << 16);
}

__device__ __forceinline__ void gload_lds16(const void* g, void* l) {
  __builtin_amdgcn_global_load_lds(
      (const __attribute__((address_space(1))) void*)g,
      (__attribute__((address_space(3))) void*)l, 16, 0, 0);
}

// ---------------------------------------------------------------------------
// f32 -> bf16 conversion (vectorized)
// ---------------------------------------------------------------------------
__global__ __launch_bounds__(256) void cvt_bf16_kernel(
    const float* __restrict__ in, unsigned short* __restrict__ out, int n4) {
  int t = blockIdx.x * 256 + threadIdx.x;
  if (t >= n4) return;
  float4 v = reinterpret_cast<const float4*>(in)[t];
  ushort4 o = make_ushort4(f2bf(v.x), f2bf(v.y), f2bf(v.z), f2bf(v.w));
  reinterpret_cast<ushort4*>(out)[t] = o;
}

// ---------------------------------------------------------------------------
// C[M,N] = A[M,K] * B[N,K]^T + bias[N]     (all bf16 in, f32 acc)
// m97 structure: 128x128 tile, BK=64, 4 waves (2x2), global_load_lds width 16
// OUT_BF16=1 -> store bf16 into C; else store f32.
// ---------------------------------------------------------------------------
template <int OUT_BF16>
__global__ __launch_bounds__(256) void gemm_bt_kernel(
    const unsigned short* __restrict__ A,
    const unsigned short* __restrict__ B,
    const float* __restrict__ bias,
    void* __restrict__ Cv,
    int M, int N, int K) {
  __shared__ unsigned short sA[128 * 64];
  __shared__ unsigned short sB[128 * 64];

  const int tid  = threadIdx.x;
  const int lane = tid & 63;
  const int wid  = tid >> 6;
  const int wm   = wid >> 1;       // 0..1
  const int wn   = wid & 1;        // 0..1
  const int tileM = blockIdx.x * 128;
  const int tileN = blockIdx.y * 128;

  f32x4 acc[4][4] = {};

  for (int k0 = 0; k0 < K; k0 += 64) {
#pragma unroll
    for (int i = 0; i < 4; ++i) {
      int li  = i * 256 + tid;          // 16B chunk index, 0..1023
      int row = li >> 3;                // 0..127
      int ce  = (li & 7) * 8;           // element offset in K within tile
      const unsigned short* ga = A + (size_t)(tileM + row) * K + k0 + ce;
      const unsigned short* gb = B + (size_t)(tileN + row) * K + k0 + ce;
      int lbase = (i * 256 + wid * 64) * 8;   // wave-uniform, elements
      gload_lds16(ga, &sA[lbase]);
      gload_lds16(gb, &sB[lbase]);
    }
    __syncthreads();

#pragma unroll
    for (int kk = 0; kk < 2; ++kk) {
      const int kof = kk * 32 + (lane >> 4) * 8;
      bf16x8 fa[4], fb[4];
#pragma unroll
      for (int f = 0; f < 4; ++f) {
        int ra = wm * 64 + f * 16 + (lane & 15);
        fa[f] = *reinterpret_cast<const bf16x8*>(&sA[ra * 64 + kof]);
        int rb = wn * 64 + f * 16 + (lane & 15);
        fb[f] = *reinterpret_cast<const bf16x8*>(&sB[rb * 64 + kof]);
      }
#pragma unroll
      for (int fi = 0; fi < 4; ++fi)
#pragma unroll
        for (int fj = 0; fj < 4; ++fj)
          acc[fi][fj] = __builtin_amdgcn_mfma_f32_16x16x32_bf16(
              fa[fi], fb[fj], acc[fi][fj], 0, 0, 0);
    }
    __syncthreads();
  }

  // epilogue: C/D layout col = lane&15, row = (lane>>4)*4 + r
#pragma unroll
  for (int fi = 0; fi < 4; ++fi) {
    int row0 = tileM + wm * 64 + fi * 16 + (lane >> 4) * 4;
#pragma unroll
    for (int fj = 0; fj < 4; ++fj) {
      int col = tileN + wn * 64 + fj * 16 + (lane & 15);
      float bs = bias[col];
#pragma unroll
      for (int r = 0; r < 4; ++r) {
        float v = acc[fi][fj][r] + bs;
        if (OUT_BF16) {
          ((unsigned short*)Cv)[(size_t)(row0 + r) * N + col] = f2bf(v);
        } else {
          ((float*)Cv)[(size_t)(row0 + r) * N + col] = v;
        }
      }
    }
  }
}

// ---------------------------------------------------------------------------
// Windowed attention: one wave per (b, h, query-row). Lane d owns dim d.
// qkv: [B*S, 3*DMODEL] bf16 (cols: q 0..1023, k 1024..2047, v 2048..3071)
// ctx: [B*S, DMODEL] bf16
// ---------------------------------------------------------------------------
__global__ __launch_bounds__(256) void attn_local_kernel(
    const unsigned short* __restrict__ qkv, unsigned short* __restrict__ ctx) {
  const int wid  = threadIdx.x >> 6;
  const int lane = threadIdx.x & 63;
  const int g = blockIdx.x * 4 + wid;      // over B*NH*S
  const int i = g & (S_LEN - 1);
  const int h = (g >> 10) & (NH - 1);
  const int b = g >> 14;

  const size_t tok = (size_t)b * S_LEN + i;
  const unsigned short* qp = qkv + tok * (3 * DMODEL) + h * HD;
  const float qd = bf2f(qp[lane]);

  int jlo = i - HALF_W; if (jlo < 0) jlo = 0;
  int jhi = i + HALF_W; if (jhi > S_LEN - 1) jhi = S_LEN - 1;
  const int cnt = jhi - jlo + 1;           // 17..33

  const unsigned short* kbase =
      qkv + ((size_t)b * S_LEN + jlo) * (3 * DMODEL) + DMODEL + h * HD;
  const unsigned short* vbase =
      qkv + ((size_t)b * S_LEN + jlo) * (3 * DMODEL) + 2 * DMODEL + h * HD;

  float s = -3.0e38f;
  for (int t = 0; t < cnt; ++t) {
    float kd = bf2f(kbase[(size_t)t * (3 * DMODEL) + lane]);
    float prod = qd * kd;
#pragma unroll
    for (int m = 32; m >= 1; m >>= 1) prod += __shfl_xor(prod, m, 64);
    if (lane == t) s = prod * 0.125f;      // 1/sqrt(64)
  }

  // softmax across lanes (lanes >= cnt hold -3e38 -> p = 0)
  float mx = s;
#pragma unroll
  for (int m = 32; m >= 1; m >>= 1) mx = fmaxf(mx, __shfl_xor(mx, m, 64));
  float p = __expf(s - mx);
  float sum = p;
#pragma unroll
  for (int m = 32; m >= 1; m >>= 1) sum += __shfl_xor(sum, m, 64);
  p /= sum;

  float c = 0.f;
  for (int t = 0; t < cnt; ++t) {
    float pj = __shfl(p, t, 64);
    float vd = bf2f(vbase[(size_t)t * (3 * DMODEL) + lane]);
    c = fmaf(pj, vd, c);
  }
  ctx[tok * DMODEL + h * HD + lane] = f2bf(c);
}

// ---------------------------------------------------------------------------
extern "C" void kernel_launch(void* const* d_in, const int* in_sizes, int n_in,
                              void* d_out, int out_size, void* d_ws, size_t ws_size,
                              hipStream_t stream) {
  const float* x     = (const float*)d_in[0];
  const float* w_in  = (const float*)d_in[1];
  const float* b_in  = (const float*)d_in[2];
  const float* w_out = (const float*)d_in[3];
  const float* b_out = (const float*)d_in[4];
  float* out = (float*)d_out;

  // workspace layout (bf16 = ushort), total ~92 MB
  unsigned short* xb   = (unsigned short*)d_ws;
  unsigned short* wib  = xb  + (size_t)8192 * 1024;
  unsigned short* wob  = wib + (size_t)3072 * 1024;
  unsigned short* qkv  = wob + (size_t)1024 * 1024;
  unsigned short* ctxb = qkv + (size_t)8192 * 3072;

  cvt_bf16_kernel<<<8192, 256, 0, stream>>>(x, xb, (8192 * 1024) / 4);
  cvt_bf16_kernel<<<3072, 256, 0, stream>>>(w_in, wib, (3072 * 1024) / 4);
  cvt_bf16_kernel<<<1024, 256, 0, stream>>>(w_out, wob, (1024 * 1024) / 4);

  // QKV = x @ w_in^T + b_in   -> [8192, 3072] bf16
  gemm_bt_kernel<1><<<dim3(64, 24), 256, 0, stream>>>(
      xb, wib, b_in, (void*)qkv, 8192, 3072, 1024);

  // windowed attention -> ctx [8192, 1024] bf16
  attn_local_kernel<<<(BATCHN * NH * S_LEN) / 4, 256, 0, stream>>>(qkv, ctxb);

  // out = ctx @ w_out^T + b_out -> [8192, 1024] f32
  gemm_bt_kernel<0><<<dim3(64, 8), 256, 0, stream>>>(
      ctxb, wob, b_out, (void*)out, 8192, 1024, 1024);
}

// Round 2
// 319.914 us; speedup vs baseline: 1.7226x; 1.7226x over previous
//
#include <hip/hip_runtime.h>

// Problem constants
#define S_LEN   1024
#define NH      16
#define HD      64
#define BATCHN  8
#define DMODEL  1024
#define HALF_W  16          // window//2

typedef __attribute__((ext_vector_type(8))) short bf16x8;   // 8 bf16 = 4 VGPRs
typedef __attribute__((ext_vector_type(4))) float f32x4;

__device__ __forceinline__ unsigned short f2bf(float f) {
  unsigned u = __builtin_bit_cast(unsigned, f);
  u += 0x7fffu + ((u >> 16) & 1u);          // round-to-nearest-even
  return (unsigned short)(u >> 16);
}
__device__ __forceinline__ float bf2f(unsigned short h) {
  return __builtin_bit_cast(float, ((unsigned)h) << 16);
}
__device__ __forceinline__ float bflo(unsigned u) {
  return __builtin_bit_cast(float, u << 16);
}
__device__ __forceinline__ float bfhi(unsigned u) {
  return __builtin_bit_cast(float, u & 0xffff0000u);
}

__device__ __forceinline__ void gload_lds16(const void* g, void* l) {
  __builtin_amdgcn_global_load_lds(
      (const __attribute__((address_space(1))) void*)g,
      (__attribute__((address_space(3))) void*)l, 16, 0, 0);
}

// ---------------------------------------------------------------------------
// f32 -> bf16 conversion (vectorized)
// ---------------------------------------------------------------------------
__global__ __launch_bounds__(256) void cvt_bf16_kernel(
    const float* __restrict__ in, unsigned short* __restrict__ out, int n4) {
  int t = blockIdx.x * 256 + threadIdx.x;
  if (t >= n4) return;
  float4 v = reinterpret_cast<const float4*>(in)[t];
  ushort4 o = make_ushort4(f2bf(v.x), f2bf(v.y), f2bf(v.z), f2bf(v.w));
  reinterpret_cast<ushort4*>(out)[t] = o;
}

// ---------------------------------------------------------------------------
// C[M,N] = A[M,K] * B[N,K]^T + bias[N]     (all bf16 in, f32 acc)
// m97 structure: 128x128 tile, BK=64, 4 waves (2x2), global_load_lds width 16
// ---------------------------------------------------------------------------
template <int OUT_BF16>
__global__ __launch_bounds__(256) void gemm_bt_kernel(
    const unsigned short* __restrict__ A,
    const unsigned short* __restrict__ B,
    const float* __restrict__ bias,
    void* __restrict__ Cv,
    int M, int N, int K) {
  __shared__ unsigned short sA[128 * 64];
  __shared__ unsigned short sB[128 * 64];

  const int tid  = threadIdx.x;
  const int lane = tid & 63;
  const int wid  = tid >> 6;
  const int wm   = wid >> 1;       // 0..1
  const int wn   = wid & 1;        // 0..1
  const int tileM = blockIdx.x * 128;
  const int tileN = blockIdx.y * 128;

  f32x4 acc[4][4] = {};

  for (int k0 = 0; k0 < K; k0 += 64) {
#pragma unroll
    for (int i = 0; i < 4; ++i) {
      int li  = i * 256 + tid;          // 16B chunk index, 0..1023
      int row = li >> 3;                // 0..127
      int ce  = (li & 7) * 8;           // element offset in K within tile
      const unsigned short* ga = A + (size_t)(tileM + row) * K + k0 + ce;
      const unsigned short* gb = B + (size_t)(tileN + row) * K + k0 + ce;
      int lbase = (i * 256 + wid * 64) * 8;   // wave-uniform, elements
      gload_lds16(ga, &sA[lbase]);
      gload_lds16(gb, &sB[lbase]);
    }
    __syncthreads();

#pragma unroll
    for (int kk = 0; kk < 2; ++kk) {
      const int kof = kk * 32 + (lane >> 4) * 8;
      bf16x8 fa[4], fb[4];
#pragma unroll
      for (int f = 0; f < 4; ++f) {
        int ra = wm * 64 + f * 16 + (lane & 15);
        fa[f] = *reinterpret_cast<const bf16x8*>(&sA[ra * 64 + kof]);
        int rb = wn * 64 + f * 16 + (lane & 15);
        fb[f] = *reinterpret_cast<const bf16x8*>(&sB[rb * 64 + kof]);
      }
#pragma unroll
      for (int fi = 0; fi < 4; ++fi)
#pragma unroll
        for (int fj = 0; fj < 4; ++fj)
          acc[fi][fj] = __builtin_amdgcn_mfma_f32_16x16x32_bf16(
              fa[fi], fb[fj], acc[fi][fj], 0, 0, 0);
    }
    __syncthreads();
  }

  // epilogue: C/D layout col = lane&15, row = (lane>>4)*4 + r
#pragma unroll
  for (int fi = 0; fi < 4; ++fi) {
    int row0 = tileM + wm * 64 + fi * 16 + (lane >> 4) * 4;
#pragma unroll
    for (int fj = 0; fj < 4; ++fj) {
      int col = tileN + wn * 64 + fj * 16 + (lane & 15);
      float bs = bias[col];
#pragma unroll
      for (int r = 0; r < 4; ++r) {
        float v = acc[fi][fj][r] + bs;
        if (OUT_BF16) {
          ((unsigned short*)Cv)[(size_t)(row0 + r) * N + col] = f2bf(v);
        } else {
          ((float*)Cv)[(size_t)(row0 + r) * N + col] = v;
        }
      }
    }
  }
}

// ---------------------------------------------------------------------------
// Windowed attention v2. Block = 4 waves handles (b, h) x 64 queries.
// Stage K,V rows [i0-16, i0+80) and Q rows [i0, i0+64) in LDS as f32.
// Score phase: lane t owns key t (serial 64-MAC dot, no cross-lane).
// Softmax: one 6+6 shuffle butterfly per query.
// PV: lane d owns output dim d; p_t via single broadcast shuffle.
// ---------------------------------------------------------------------------
#define KV_STRIDE 66   // dwords; (66*r + d) % 32 = (2r + d) % 32 -> 2-way alias (free)

__global__ __launch_bounds__(256) void attn_local_kernel(
    const unsigned short* __restrict__ qkv, unsigned short* __restrict__ ctx) {
  __shared__ float sK[96 * KV_STRIDE];
  __shared__ float sV[96 * KV_STRIDE];
  __shared__ float sQ[64 * 64];

  const int tid  = threadIdx.x;
  const int lane = tid & 63;
  const int wid  = tid >> 6;

  const int qb = blockIdx.x & 15;         // S/64 = 16
  const int h  = (blockIdx.x >> 4) & 15;
  const int b  = blockIdx.x >> 8;
  const int i0 = qb * 64;

  const unsigned short* hb = qkv + (size_t)b * S_LEN * 3072 + (size_t)h * HD;

  // ---- stage K/V (f32) ----
  for (int c = tid; c < 96 * 32; c += 256) {   // dword-pair per row: 32
    int r = c >> 5, p = c & 31;
    int j = i0 - 16 + r;
    if (0 <= j && j < S_LEN) {
      const unsigned short* rp = hb + (size_t)j * 3072;
      unsigned ku = *reinterpret_cast<const unsigned*>(rp + DMODEL + 2 * p);
      unsigned vu = *reinterpret_cast<const unsigned*>(rp + 2 * DMODEL + 2 * p);
      sK[r * KV_STRIDE + 2 * p]     = bflo(ku);
      sK[r * KV_STRIDE + 2 * p + 1] = bfhi(ku);
      sV[r * KV_STRIDE + 2 * p]     = bflo(vu);
      sV[r * KV_STRIDE + 2 * p + 1] = bfhi(vu);
    }
  }
  // ---- stage Q (f32) ----
  for (int c = tid; c < 64 * 32; c += 256) {
    int r = c >> 5, p = c & 31;
    const unsigned short* rp = hb + (size_t)(i0 + r) * 3072;
    unsigned qu = *reinterpret_cast<const unsigned*>(rp + 2 * p);
    sQ[r * 64 + 2 * p]     = bflo(qu);
    sQ[r * 64 + 2 * p + 1] = bfhi(qu);
  }
  __syncthreads();

#pragma unroll 1
  for (int qq = 0; qq < 16; ++qq) {
    const int iq = wid * 16 + qq;          // local query 0..63
    const int i  = i0 + iq;                // global query row
    int jlo = i - HALF_W; if (jlo < 0) jlo = 0;
    int jhi = i + HALF_W; if (jhi > S_LEN - 1) jhi = S_LEN - 1;
    const int cnt   = jhi - jlo + 1;       // 17..33, wave-uniform
    const int rbase = jlo - (i0 - 16);     // 0..79
    int r = rbase + lane; if (r > 95) r = 95;   // clamp unused lanes in-bounds

    const float* kp = &sK[r * KV_STRIDE];
    const float* qp = &sQ[iq * 64];

    float a0 = 0.f, a1 = 0.f;
#pragma unroll
    for (int d = 0; d < 64; d += 4) {
      float4 qv  = *reinterpret_cast<const float4*>(qp + d);   // uniform bcast
      float2 kv0 = *reinterpret_cast<const float2*>(kp + d);
      float2 kv1 = *reinterpret_cast<const float2*>(kp + d + 2);
      a0 = fmaf(qv.x, kv0.x, a0);
      a0 = fmaf(qv.y, kv0.y, a0);
      a1 = fmaf(qv.z, kv1.x, a1);
      a1 = fmaf(qv.w, kv1.y, a1);
    }
    float s = (lane < cnt) ? (a0 + a1) * 0.125f : -3.0e38f;

    // softmax over 64 lanes
    float mx = s;
#pragma unroll
    for (int m = 32; m >= 1; m >>= 1) mx = fmaxf(mx, __shfl_xor(mx, m, 64));
    float p = __expf(s - mx);
    float sum = p;
#pragma unroll
    for (int m = 32; m >= 1; m >>= 1) sum += __shfl_xor(sum, m, 64);
    p /= sum;

    // PV: lane owns output dim = lane
    float o = 0.f;
    for (int t = 0; t < cnt; ++t) {
      float pt = __shfl(p, t, 64);
      o = fmaf(pt, sV[(rbase + t) * KV_STRIDE + lane], o);
    }
    ctx[((size_t)b * S_LEN + i) * DMODEL + h * HD + lane] = f2bf(o);
  }
}

// ---------------------------------------------------------------------------
extern "C" void kernel_launch(void* const* d_in, const int* in_sizes, int n_in,
                              void* d_out, int out_size, void* d_ws, size_t ws_size,
                              hipStream_t stream) {
  const float* x     = (const float*)d_in[0];
  const float* w_in  = (const float*)d_in[1];
  const float* b_in  = (const float*)d_in[2];
  const float* w_out = (const float*)d_in[3];
  const float* b_out = (const float*)d_in[4];
  float* out = (float*)d_out;

  // workspace layout (bf16 = ushort), total ~92 MB
  unsigned short* xb   = (unsigned short*)d_ws;
  unsigned short* wib  = xb  + (size_t)8192 * 1024;
  unsigned short* wob  = wib + (size_t)3072 * 1024;
  unsigned short* qkv  = wob + (size_t)1024 * 1024;
  unsigned short* ctxb = qkv + (size_t)8192 * 3072;

  cvt_bf16_kernel<<<8192, 256, 0, stream>>>(x, xb, (8192 * 1024) / 4);
  cvt_bf16_kernel<<<3072, 256, 0, stream>>>(w_in, wib, (3072 * 1024) / 4);
  cvt_bf16_kernel<<<1024, 256, 0, stream>>>(w_out, wob, (1024 * 1024) / 4);

  // QKV = x @ w_in^T + b_in   -> [8192, 3072] bf16
  gemm_bt_kernel<1><<<dim3(64, 24), 256, 0, stream>>>(
      xb, wib, b_in, (void*)qkv, 8192, 3072, 1024);

  // windowed attention -> ctx [8192, 1024] bf16
  attn_local_kernel<<<BATCHN * NH * (S_LEN / 64), 256, 0, stream>>>(qkv, ctxb);

  // out = ctx @ w_out^T + b_out -> [8192, 1024] f32
  gemm_bt_kernel<0><<<dim3(64, 8), 256, 0, stream>>>(
      ctxb, wob, b_out, (void*)out, 8192, 1024, 1024);
}

// Round 4
// 145.534 us; speedup vs baseline: 3.7867x; 2.1982x over previous
//
#include <hip/hip_runtime.h>

// Problem constants
#define S_LEN   1024
#define NH      16
#define HD      64
#define BATCHN  8
#define DMODEL  1024
#define HALF_W  16          // window//2

typedef __attribute__((ext_vector_type(8))) short bf16x8;   // 8 bf16 = 4 VGPRs
typedef __attribute__((ext_vector_type(4))) float f32x4;

__device__ __forceinline__ unsigned short f2bf(float f) {
  unsigned u = __builtin_bit_cast(unsigned, f);
  u += 0x7fffu + ((u >> 16) & 1u);          // round-to-nearest-even
  return (unsigned short)(u >> 16);
}
__device__ __forceinline__ float bf2f(unsigned short h) {
  return __builtin_bit_cast(float, ((unsigned)h) << 16);
}

__device__ __forceinline__ void gload_lds16(const void* g, void* l) {
  __builtin_amdgcn_global_load_lds(
      (const __attribute__((address_space(1))) void*)g,
      (__attribute__((address_space(3))) void*)l, 16, 0, 0);
}

// ---------------------------------------------------------------------------
// f32 -> bf16 conversion (vectorized)
// ---------------------------------------------------------------------------
__global__ __launch_bounds__(256) void cvt_bf16_kernel(
    const float* __restrict__ in, unsigned short* __restrict__ out, int n4) {
  int t = blockIdx.x * 256 + threadIdx.x;
  if (t >= n4) return;
  float4 v = reinterpret_cast<const float4*>(in)[t];
  ushort4 o = make_ushort4(f2bf(v.x), f2bf(v.y), f2bf(v.z), f2bf(v.w));
  reinterpret_cast<ushort4*>(out)[t] = o;
}

// ---------------------------------------------------------------------------
// C[M,N] = A[M,K] * B[N,K]^T + bias[N]     (all bf16 in, f32 acc)
// m97 structure: 128x128 tile, BK=64, 4 waves (2x2), global_load_lds width 16
// ---------------------------------------------------------------------------
template <int OUT_BF16>
__global__ __launch_bounds__(256) void gemm_bt_kernel(
    const unsigned short* __restrict__ A,
    const unsigned short* __restrict__ B,
    const float* __restrict__ bias,
    void* __restrict__ Cv,
    int M, int N, int K) {
  __shared__ unsigned short sA[128 * 64];
  __shared__ unsigned short sB[128 * 64];

  const int tid  = threadIdx.x;
  const int lane = tid & 63;
  const int wid  = tid >> 6;
  const int wm   = wid >> 1;       // 0..1
  const int wn   = wid & 1;        // 0..1
  const int tileM = blockIdx.x * 128;
  const int tileN = blockIdx.y * 128;

  f32x4 acc[4][4] = {};

  for (int k0 = 0; k0 < K; k0 += 64) {
#pragma unroll
    for (int i = 0; i < 4; ++i) {
      int li  = i * 256 + tid;          // 16B chunk index, 0..1023
      int row = li >> 3;                // 0..127
      int ce  = (li & 7) * 8;           // element offset in K within tile
      const unsigned short* ga = A + (size_t)(tileM + row) * K + k0 + ce;
      const unsigned short* gb = B + (size_t)(tileN + row) * K + k0 + ce;
      int lbase = (i * 256 + wid * 64) * 8;   // wave-uniform, elements
      gload_lds16(ga, &sA[lbase]);
      gload_lds16(gb, &sB[lbase]);
    }
    __syncthreads();

#pragma unroll
    for (int kk = 0; kk < 2; ++kk) {
      const int kof = kk * 32 + (lane >> 4) * 8;
      bf16x8 fa[4], fb[4];
#pragma unroll
      for (int f = 0; f < 4; ++f) {
        int ra = wm * 64 + f * 16 + (lane & 15);
        fa[f] = *reinterpret_cast<const bf16x8*>(&sA[ra * 64 + kof]);
        int rb = wn * 64 + f * 16 + (lane & 15);
        fb[f] = *reinterpret_cast<const bf16x8*>(&sB[rb * 64 + kof]);
      }
#pragma unroll
      for (int fi = 0; fi < 4; ++fi)
#pragma unroll
        for (int fj = 0; fj < 4; ++fj)
          acc[fi][fj] = __builtin_amdgcn_mfma_f32_16x16x32_bf16(
              fa[fi], fb[fj], acc[fi][fj], 0, 0, 0);
    }
    __syncthreads();
  }

  // epilogue: C/D layout col = lane&15, row = (lane>>4)*4 + r
#pragma unroll
  for (int fi = 0; fi < 4; ++fi) {
    int row0 = tileM + wm * 64 + fi * 16 + (lane >> 4) * 4;
#pragma unroll
    for (int fj = 0; fj < 4; ++fj) {
      int col = tileN + wn * 64 + fj * 16 + (lane & 15);
      float bs = bias[col];
#pragma unroll
      for (int r = 0; r < 4; ++r) {
        float v = acc[fi][fj][r] + bs;
        if (OUT_BF16) {
          ((unsigned short*)Cv)[(size_t)(row0 + r) * N + col] = f2bf(v);
        } else {
          ((float*)Cv)[(size_t)(row0 + r) * N + col] = v;
        }
      }
    }
  }
}

// ---------------------------------------------------------------------------
// Windowed attention v3 (MFMA). Block = (b, h, 64-query tile), 4 waves.
// Wave w owns queries [16w, 16w+16), all 96 window keys [i0-16, i0+80).
// Phase 1: S^T[96x16] = mfma(K-frag, Q-frag); mask+softmax in registers
//          (24 in-lane values + shfl_xor 16/32); write unnormalized P bf16
//          to LDS (overlays sK). 1/sum folded into epilogue.
// Phase 2: ctx^T[64x16] = mfma(V^T-frag, P-frag); scale by 1/sum; store.
// ---------------------------------------------------------------------------
#define KST 72    // sK/sQ stride (bf16): 144B rows -> 2-way bank alias (free)
#define PST 104   // sVT/sP stride (bf16): 208B rows -> uniform 2-way

__global__ __launch_bounds__(256) void attn_local_kernel(
    const unsigned short* __restrict__ qkv, unsigned short* __restrict__ ctx) {
  __shared__ __align__(16) unsigned short sKP[96 * KST];   // K, later P
  __shared__ __align__(16) unsigned short sQ[64 * KST];
  __shared__ __align__(16) unsigned short sVT[64 * PST];

  const int tid  = threadIdx.x;
  const int lane = tid & 63;
  const int wid  = tid >> 6;
  const int qc   = lane & 15;        // query col within wave's 16
  const int lgrp = lane >> 4;        // 0..3

  const int qb = blockIdx.x & 15;    // S/64 = 16
  const int h  = (blockIdx.x >> 4) & 15;
  const int b  = blockIdx.x >> 8;
  const int i0 = qb * 64;

  const unsigned short* hb = qkv + (size_t)b * S_LEN * 3072 + (size_t)h * HD;

  // ---- stage K [96][KST] and V^T [64][PST] ----
#pragma unroll
  for (int it = 0; it < 3; ++it) {
    int c  = it * 256 + tid;         // 0..767
    int r  = c >> 3;                 // key row 0..95
    int d0 = (c & 7) * 8;            // dim chunk
    int j  = i0 - 16 + r;
    bf16x8 kv = {}, vv = {};
    if (0 <= j && j < S_LEN) {
      const unsigned short* rp = hb + (size_t)j * 3072;
      kv = *reinterpret_cast<const bf16x8*>(rp + DMODEL + d0);
      vv = *reinterpret_cast<const bf16x8*>(rp + 2 * DMODEL + d0);
    }
    *reinterpret_cast<bf16x8*>(&sKP[r * KST + d0]) = kv;
    // V transpose: rotate write order so the 8 lanes of a d0-group hit
    // 8 distinct banks
#pragma unroll
    for (int jj = 0; jj < 8; ++jj) {
      int dd = (jj + c) & 7;
      sVT[(d0 + dd) * PST + r] = (unsigned short)vv[dd];
    }
  }
  // ---- stage Q [64][KST] ----
#pragma unroll
  for (int it = 0; it < 2; ++it) {
    int c  = it * 256 + tid;         // 0..511
    int r  = c >> 3;                 // query row 0..63
    int d0 = (c & 7) * 8;
    bf16x8 qv = *reinterpret_cast<const bf16x8*>(hb + (size_t)(i0 + r) * 3072 + d0);
    *reinterpret_cast<bf16x8*>(&sQ[r * KST + d0]) = qv;
  }
  __syncthreads();

  const int q0 = wid * 16;

  // ---- phase 1: S^T = K @ Q^T  (12 MFMA) ----
  bf16x8 bq[2];
#pragma unroll
  for (int ks = 0; ks < 2; ++ks)
    bq[ks] = *reinterpret_cast<const bf16x8*>(
        &sQ[(q0 + qc) * KST + ks * 32 + lgrp * 8]);

  f32x4 st[6] = {};
#pragma unroll
  for (int kt = 0; kt < 6; ++kt) {
#pragma unroll
    for (int ks = 0; ks < 2; ++ks) {
      bf16x8 fa = *reinterpret_cast<const bf16x8*>(
          &sKP[(kt * 16 + qc) * KST + ks * 32 + lgrp * 8]);
      st[kt] = __builtin_amdgcn_mfma_f32_16x16x32_bf16(fa, bq[ks], st[kt], 0, 0, 0);
    }
  }
  __syncthreads();   // all waves done reading sKP before P overlays it

  // ---- mask + softmax (keys for query q0+qc spread over 24 regs x 4 lgrps) ----
  const int q = q0 + qc;
  float pv[6][4];
  float mx = -3.0e38f;
#pragma unroll
  for (int kt = 0; kt < 6; ++kt)
#pragma unroll
    for (int rr = 0; rr < 4; ++rr) {
      int kk = kt * 16 + lgrp * 4 + rr;     // local key 0..95
      int j  = i0 - 16 + kk;
      bool ok = (j >= 0) && (j < S_LEN) && (kk >= q) && (kk <= q + 32);
      float s = ok ? st[kt][rr] * 0.125f : -3.0e38f;
      pv[kt][rr] = s;
      mx = fmaxf(mx, s);
    }
  mx = fmaxf(mx, __shfl_xor(mx, 16, 64));
  mx = fmaxf(mx, __shfl_xor(mx, 32, 64));

  float rsum = 0.f;
#pragma unroll
  for (int kt = 0; kt < 6; ++kt)
#pragma unroll
    for (int rr = 0; rr < 4; ++rr) {
      float p = __expf(pv[kt][rr] - mx);
      pv[kt][rr] = p;
      rsum += p;
    }
  rsum += __shfl_xor(rsum, 16, 64);
  rsum += __shfl_xor(rsum, 32, 64);
  const float inv = 1.0f / rsum;

  // ---- write unnormalized P bf16 into sP = sKP, layout [q][k] stride PST ----
  unsigned short* sP = sKP;
#pragma unroll
  for (int kt = 0; kt < 6; ++kt) {
    ushort4 w = make_ushort4(f2bf(pv[kt][0]), f2bf(pv[kt][1]),
                             f2bf(pv[kt][2]), f2bf(pv[kt][3]));
    *reinterpret_cast<ushort4*>(&sP[(q0 + qc) * PST + kt * 16 + lgrp * 4]) = w;
  }

  // ---- phase 2: ctx^T = V^T @ P^T  (12 MFMA) ----
  bf16x8 pb[3];
#pragma unroll
  for (int ks = 0; ks < 3; ++ks)
    pb[ks] = *reinterpret_cast<const bf16x8*>(
        &sP[(q0 + qc) * PST + ks * 32 + lgrp * 8]);

  f32x4 ct[4] = {};
#pragma unroll
  for (int dt = 0; dt < 4; ++dt)
#pragma unroll
    for (int ks = 0; ks < 3; ++ks) {
      bf16x8 fa = *reinterpret_cast<const bf16x8*>(
          &sVT[(dt * 16 + qc) * PST + ks * 32 + lgrp * 8]);
      ct[dt] = __builtin_amdgcn_mfma_f32_16x16x32_bf16(fa, pb[ks], ct[dt], 0, 0, 0);
    }

  // ---- epilogue: scale by 1/sum (col = lane&15 = same query), store 8B ----
  unsigned short* op =
      ctx + ((size_t)b * S_LEN + i0 + q0 + qc) * DMODEL + h * HD;
#pragma unroll
  for (int dt = 0; dt < 4; ++dt) {
    ushort4 w = make_ushort4(
        f2bf(ct[dt][0] * inv), f2bf(ct[dt][1] * inv),
        f2bf(ct[dt][2] * inv), f2bf(ct[dt][3] * inv));
    *reinterpret_cast<ushort4*>(op + dt * 16 + lgrp * 4) = w;
  }
}

// ---------------------------------------------------------------------------
extern "C" void kernel_launch(void* const* d_in, const int* in_sizes, int n_in,
                              void* d_out, int out_size, void* d_ws, size_t ws_size,
                              hipStream_t stream) {
  const float* x     = (const float*)d_in[0];
  const float* w_in  = (const float*)d_in[1];
  const float* b_in  = (const float*)d_in[2];
  const float* w_out = (const float*)d_in[3];
  const float* b_out = (const float*)d_in[4];
  float* out = (float*)d_out;

  // workspace layout (bf16 = ushort), total ~92 MB
  unsigned short* xb   = (unsigned short*)d_ws;
  unsigned short* wib  = xb  + (size_t)8192 * 1024;
  unsigned short* wob  = wib + (size_t)3072 * 1024;
  unsigned short* qkv  = wob + (size_t)1024 * 1024;
  unsigned short* ctxb = qkv + (size_t)8192 * 3072;

  cvt_bf16_kernel<<<8192, 256, 0, stream>>>(x, xb, (8192 * 1024) / 4);
  cvt_bf16_kernel<<<3072, 256, 0, stream>>>(w_in, wib, (3072 * 1024) / 4);
  cvt_bf16_kernel<<<1024, 256, 0, stream>>>(w_out, wob, (1024 * 1024) / 4);

  // QKV = x @ w_in^T + b_in   -> [8192, 3072] bf16
  gemm_bt_kernel<1><<<dim3(64, 24), 256, 0, stream>>>(
      xb, wib, b_in, (void*)qkv, 8192, 3072, 1024);

  // windowed attention -> ctx [8192, 1024] bf16
  attn_local_kernel<<<BATCHN * NH * (S_LEN / 64), 256, 0, stream>>>(qkv, ctxb);

  // out = ctx @ w_out^T + b_out -> [8192, 1024] f32
  gemm_bt_kernel<0><<<dim3(64, 8), 256, 0, stream>>>(
      ctxb, wob, b_out, (void*)out, 8192, 1024, 1024);
}

// Round 5
// 140.221 us; speedup vs baseline: 3.9302x; 1.0379x over previous
//
#include <hip/hip_runtime.h>

// Problem constants
#define S_LEN   1024
#define NH      16
#define HD      64
#define BATCHN  8
#define DMODEL  1024
#define HALF_W  16          // window//2

typedef __attribute__((ext_vector_type(8))) short bf16x8;   // 8 bf16 = 4 VGPRs
typedef __attribute__((ext_vector_type(4))) float f32x4;

__device__ __forceinline__ unsigned short f2bf(float f) {
  unsigned u = __builtin_bit_cast(unsigned, f);
  u += 0x7fffu + ((u >> 16) & 1u);          // round-to-nearest-even
  return (unsigned short)(u >> 16);
}
__device__ __forceinline__ float bf2f(unsigned short h) {
  return __builtin_bit_cast(float, ((unsigned)h) << 16);
}

__device__ __forceinline__ void gload_lds16(const void* g, void* l) {
  __builtin_amdgcn_global_load_lds(
      (const __attribute__((address_space(1))) void*)g,
      (__attribute__((address_space(3))) void*)l, 16, 0, 0);
}

// ---------------------------------------------------------------------------
// f32 -> bf16 conversion (vectorized)
// ---------------------------------------------------------------------------
__global__ __launch_bounds__(256) void cvt_bf16_kernel(
    const float* __restrict__ in, unsigned short* __restrict__ out, int n4) {
  int t = blockIdx.x * 256 + threadIdx.x;
  if (t >= n4) return;
  float4 v = reinterpret_cast<const float4*>(in)[t];
  ushort4 o = make_ushort4(f2bf(v.x), f2bf(v.y), f2bf(v.z), f2bf(v.w));
  reinterpret_cast<ushort4*>(out)[t] = o;
}

// ---------------------------------------------------------------------------
// Phased GEMM: C[M,N] = A[M,K] * B[N,K]^T + bias[N]  (bf16 in, f32 acc)
// Tile 256x128, BK=64, 8 waves (4m x 2n), per-wave 64x64.
// 4 phases per iteration (2 K-tiles), counted vmcnt(3), raw s_barrier,
// T2 LDS XOR-swizzle (col ^= (row&7)<<3) via pre-swizzled global source,
// T5 setprio around MFMA clusters, T1 XCD-aware block swizzle.
// LDS: 2 x (A 256x64 + B 128x64) bf16 = 96 KiB -> 1 block/CU, 8 waves.
// ---------------------------------------------------------------------------
#define GMT 256
#define GNT 128
#define GBK 64

template <int OUT_BF16>
__global__ __launch_bounds__(512, 2) void gemm8p_kernel(
    const unsigned short* __restrict__ A,
    const unsigned short* __restrict__ B,
    const float* __restrict__ bias,
    void* __restrict__ Cv,
    int M, int N, int K, int gy) {
  __shared__ __align__(16) unsigned short sA[2][GMT * GBK];
  __shared__ __align__(16) unsigned short sB[2][GNT * GBK];

  const int tid  = threadIdx.x;
  const int lane = tid & 63;
  const int wid  = tid >> 6;       // 0..7
  const int wm   = wid >> 1;       // 0..3
  const int wn   = wid & 1;        // 0..1
  const int lgrp = lane >> 4;      // 0..3
  const int l15  = lane & 15;
  const int swz  = (lane & 7) << 3;

  // T1: XCD-aware bijective swizzle (nwg % 8 == 0 by construction)
  const int nwg = gridDim.x;
  const int cpx = nwg >> 3;
  const int sid = (blockIdx.x & 7) * cpx + (blockIdx.x >> 3);
  const int tileM = (sid / gy) * GMT;
  const int tileN = (sid % gy) * GNT;

  // staging: thread t covers chunk element row r_c = t>>3, cols [(t&7)*8, +8)
  // pre-swizzled SOURCE col so that linear LDS dest + swizzled read = correct
  const int r_c   = tid >> 3;                       // 0..63
  const int c_src = ((tid & 7) * 8) ^ ((r_c & 7) << 3);
  const unsigned short* gA = A + (size_t)(tileM + r_c) * K + c_src;
  const unsigned short* gB = B + (size_t)(tileN + r_c) * K + c_src;

#define STAGE_G0(kt, buf) do { const int k0_ = (kt) * GBK;                 \
    gload_lds16(gA + k0_,             &sA[buf][tid * 8]);                  \
    gload_lds16(gA + k0_ + 64  * K,   &sA[buf][4096  + tid * 8]);          \
    gload_lds16(gA + k0_ + 128 * K,   &sA[buf][8192  + tid * 8]); } while(0)
#define STAGE_G1(kt, buf) do { const int k0_ = (kt) * GBK;                 \
    gload_lds16(gA + k0_ + 192 * K,   &sA[buf][12288 + tid * 8]);          \
    gload_lds16(gB + k0_,             &sB[buf][tid * 8]);                  \
    gload_lds16(gB + k0_ + 64  * K,   &sB[buf][4096  + tid * 8]); } while(0)

  // fragment read offsets (elements); col field already includes swizzle
  const int aoff = (wm * 64 + l15) * GBK;
  const int boff = (wn * 64 + l15) * GBK;
  const int c0 = (lgrp * 8) ^ swz;        // ks = 0
  const int c1 = (32 + lgrp * 8) ^ swz;   // ks = 1

  f32x4 acc[4][4] = {};

  // prologue: stage kt0 into buf0
  STAGE_G0(0, 0);
  STAGE_G1(0, 0);

  const int NKT = K >> 6;                 // even (K = 1024 -> 16)
  for (int kt = 0; kt < NKT; kt += 2) {
    const bool morek = (kt + 2 < NKT);
    bf16x8 a0[4], a1[4], b0[2], b1[2];

    // ===== phase 0: compute kt (buf0) x B-left; stage kt+1 G0 -> buf1 =====
    STAGE_G0(kt + 1, 1);
    asm volatile("s_waitcnt vmcnt(3)" ::: "memory");   // kt's 6 loads done
    __builtin_amdgcn_sched_barrier(0);
    __builtin_amdgcn_s_barrier();                      // buf0 valid for all
#pragma unroll
    for (int m = 0; m < 4; ++m) {
      a0[m] = *reinterpret_cast<const bf16x8*>(&sA[0][aoff + m * 1024 + c0]);
      a1[m] = *reinterpret_cast<const bf16x8*>(&sA[0][aoff + m * 1024 + c1]);
    }
#pragma unroll
    for (int n = 0; n < 2; ++n) {
      b0[n] = *reinterpret_cast<const bf16x8*>(&sB[0][boff + n * 1024 + c0]);
      b1[n] = *reinterpret_cast<const bf16x8*>(&sB[0][boff + n * 1024 + c1]);
    }
    asm volatile("s_waitcnt lgkmcnt(0)" ::: "memory");
    __builtin_amdgcn_sched_barrier(0);
    __builtin_amdgcn_s_setprio(1);
#pragma unroll
    for (int m = 0; m < 4; ++m)
#pragma unroll
      for (int n = 0; n < 2; ++n) {
        acc[m][n] = __builtin_amdgcn_mfma_f32_16x16x32_bf16(a0[m], b0[n], acc[m][n], 0, 0, 0);
        acc[m][n] = __builtin_amdgcn_mfma_f32_16x16x32_bf16(a1[m], b1[n], acc[m][n], 0, 0, 0);
      }
    __builtin_amdgcn_s_setprio(0);
    __builtin_amdgcn_s_barrier();

    // ===== phase 1: compute kt x B-right; stage kt+1 G1 -> buf1 =====
#pragma unroll
    for (int n = 0; n < 2; ++n) {
      b0[n] = *reinterpret_cast<const bf16x8*>(&sB[0][boff + 2048 + n * 1024 + c0]);
      b1[n] = *reinterpret_cast<const bf16x8*>(&sB[0][boff + 2048 + n * 1024 + c1]);
    }
    STAGE_G1(kt + 1, 1);
    __builtin_amdgcn_sched_barrier(0);
    __builtin_amdgcn_s_barrier();
    asm volatile("s_waitcnt lgkmcnt(0)" ::: "memory");
    __builtin_amdgcn_sched_barrier(0);
    __builtin_amdgcn_s_setprio(1);
#pragma unroll
    for (int m = 0; m < 4; ++m)
#pragma unroll
      for (int n = 0; n < 2; ++n) {
        acc[m][2 + n] = __builtin_amdgcn_mfma_f32_16x16x32_bf16(a0[m], b0[n], acc[m][2 + n], 0, 0, 0);
        acc[m][2 + n] = __builtin_amdgcn_mfma_f32_16x16x32_bf16(a1[m], b1[n], acc[m][2 + n], 0, 0, 0);
      }
    __builtin_amdgcn_s_setprio(0);
    __builtin_amdgcn_s_barrier();

    // ===== phase 2: compute kt+1 (buf1) x B-left; stage kt+2 G0 -> buf0 =====
    if (morek) {
      STAGE_G0(kt + 2, 0);
      asm volatile("s_waitcnt vmcnt(3)" ::: "memory");  // kt+1's 6 loads done
    } else {
      asm volatile("s_waitcnt vmcnt(0)" ::: "memory");
    }
    __builtin_amdgcn_sched_barrier(0);
    __builtin_amdgcn_s_barrier();                       // buf1 valid for all
#pragma unroll
    for (int m = 0; m < 4; ++m) {
      a0[m] = *reinterpret_cast<const bf16x8*>(&sA[1][aoff + m * 1024 + c0]);
      a1[m] = *reinterpret_cast<const bf16x8*>(&sA[1][aoff + m * 1024 + c1]);
    }
#pragma unroll
    for (int n = 0; n < 2; ++n) {
      b0[n] = *reinterpret_cast<const bf16x8*>(&sB[1][boff + n * 1024 + c0]);
      b1[n] = *reinterpret_cast<const bf16x8*>(&sB[1][boff + n * 1024 + c1]);
    }
    asm volatile("s_waitcnt lgkmcnt(0)" ::: "memory");
    __builtin_amdgcn_sched_barrier(0);
    __builtin_amdgcn_s_setprio(1);
#pragma unroll
    for (int m = 0; m < 4; ++m)
#pragma unroll
      for (int n = 0; n < 2; ++n) {
        acc[m][n] = __builtin_amdgcn_mfma_f32_16x16x32_bf16(a0[m], b0[n], acc[m][n], 0, 0, 0);
        acc[m][n] = __builtin_amdgcn_mfma_f32_16x16x32_bf16(a1[m], b1[n], acc[m][n], 0, 0, 0);
      }
    __builtin_amdgcn_s_setprio(0);
    __builtin_amdgcn_s_barrier();

    // ===== phase 3: compute kt+1 x B-right; stage kt+2 G1 -> buf0 =====
#pragma unroll
    for (int n = 0; n < 2; ++n) {
      b0[n] = *reinterpret_cast<const bf16x8*>(&sB[1][boff + 2048 + n * 1024 + c0]);
      b1[n] = *reinterpret_cast<const bf16x8*>(&sB[1][boff + 2048 + n * 1024 + c1]);
    }
    if (morek) STAGE_G1(kt + 2, 0);
    __builtin_amdgcn_sched_barrier(0);
    __builtin_amdgcn_s_barrier();
    asm volatile("s_waitcnt lgkmcnt(0)" ::: "memory");
    __builtin_amdgcn_sched_barrier(0);
    __builtin_amdgcn_s_setprio(1);
#pragma unroll
    for (int m = 0; m < 4; ++m)
#pragma unroll
      for (int n = 0; n < 2; ++n) {
        acc[m][2 + n] = __builtin_amdgcn_mfma_f32_16x16x32_bf16(a0[m], b0[n], acc[m][2 + n], 0, 0, 0);
        acc[m][2 + n] = __builtin_amdgcn_mfma_f32_16x16x32_bf16(a1[m], b1[n], acc[m][2 + n], 0, 0, 0);
      }
    __builtin_amdgcn_s_setprio(0);
    __builtin_amdgcn_s_barrier();
  }
#undef STAGE_G0
#undef STAGE_G1

  // epilogue: C/D layout col = lane&15, row = (lane>>4)*4 + rr
#pragma unroll
  for (int n = 0; n < 4; ++n) {
    const int col = tileN + wn * 64 + n * 16 + l15;
    const float bs = bias[col];
#pragma unroll
    for (int m = 0; m < 4; ++m) {
      const int row0 = tileM + wm * 64 + m * 16 + lgrp * 4;
#pragma unroll
      for (int rr = 0; rr < 4; ++rr) {
        float v = acc[m][n][rr] + bs;
        if (OUT_BF16) {
          ((unsigned short*)Cv)[(size_t)(row0 + rr) * N + col] = f2bf(v);
        } else {
          ((float*)Cv)[(size_t)(row0 + rr) * N + col] = v;
        }
      }
    }
  }
}

// ---------------------------------------------------------------------------
// Windowed attention v3 (MFMA). Block = (b, h, 64-query tile), 4 waves.
// ---------------------------------------------------------------------------
#define KST 72    // sK/sQ stride (bf16): 144B rows -> 2-way bank alias (free)
#define PST 104   // sVT/sP stride (bf16): 208B rows -> uniform 2-way

__global__ __launch_bounds__(256) void attn_local_kernel(
    const unsigned short* __restrict__ qkv, unsigned short* __restrict__ ctx) {
  __shared__ __align__(16) unsigned short sKP[96 * KST];   // K, later P
  __shared__ __align__(16) unsigned short sQ[64 * KST];
  __shared__ __align__(16) unsigned short sVT[64 * PST];

  const int tid  = threadIdx.x;
  const int lane = tid & 63;
  const int wid  = tid >> 6;
  const int qc   = lane & 15;        // query col within wave's 16
  const int lgrp = lane >> 4;        // 0..3

  const int qb = blockIdx.x & 15;    // S/64 = 16
  const int h  = (blockIdx.x >> 4) & 15;
  const int b  = blockIdx.x >> 8;
  const int i0 = qb * 64;

  const unsigned short* hb = qkv + (size_t)b * S_LEN * 3072 + (size_t)h * HD;

  // ---- stage K [96][KST] and V^T [64][PST] ----
#pragma unroll
  for (int it = 0; it < 3; ++it) {
    int c  = it * 256 + tid;         // 0..767
    int r  = c >> 3;                 // key row 0..95
    int d0 = (c & 7) * 8;            // dim chunk
    int j  = i0 - 16 + r;
    bf16x8 kv = {}, vv = {};
    if (0 <= j && j < S_LEN) {
      const unsigned short* rp = hb + (size_t)j * 3072;
      kv = *reinterpret_cast<const bf16x8*>(rp + DMODEL + d0);
      vv = *reinterpret_cast<const bf16x8*>(rp + 2 * DMODEL + d0);
    }
    *reinterpret_cast<bf16x8*>(&sKP[r * KST + d0]) = kv;
#pragma unroll
    for (int jj = 0; jj < 8; ++jj) {
      int dd = (jj + c) & 7;
      sVT[(d0 + dd) * PST + r] = (unsigned short)vv[dd];
    }
  }
  // ---- stage Q [64][KST] ----
#pragma unroll
  for (int it = 0; it < 2; ++it) {
    int c  = it * 256 + tid;         // 0..511
    int r  = c >> 3;                 // query row 0..63
    int d0 = (c & 7) * 8;
    bf16x8 qv = *reinterpret_cast<const bf16x8*>(hb + (size_t)(i0 + r) * 3072 + d0);
    *reinterpret_cast<bf16x8*>(&sQ[r * KST + d0]) = qv;
  }
  __syncthreads();

  const int q0 = wid * 16;

  // ---- phase 1: S^T = K @ Q^T  (12 MFMA) ----
  bf16x8 bq[2];
#pragma unroll
  for (int ks = 0; ks < 2; ++ks)
    bq[ks] = *reinterpret_cast<const bf16x8*>(
        &sQ[(q0 + qc) * KST + ks * 32 + lgrp * 8]);

  f32x4 st[6] = {};
#pragma unroll
  for (int kt = 0; kt < 6; ++kt) {
#pragma unroll
    for (int ks = 0; ks < 2; ++ks) {
      bf16x8 fa = *reinterpret_cast<const bf16x8*>(
          &sKP[(kt * 16 + qc) * KST + ks * 32 + lgrp * 8]);
      st[kt] = __builtin_amdgcn_mfma_f32_16x16x32_bf16(fa, bq[ks], st[kt], 0, 0, 0);
    }
  }
  __syncthreads();   // all waves done reading sKP before P overlays it

  // ---- mask + softmax ----
  const int q = q0 + qc;
  float pv[6][4];
  float mx = -3.0e38f;
#pragma unroll
  for (int kt = 0; kt < 6; ++kt)
#pragma unroll
    for (int rr = 0; rr < 4; ++rr) {
      int kk = kt * 16 + lgrp * 4 + rr;     // local key 0..95
      int j  = i0 - 16 + kk;
      bool ok = (j >= 0) && (j < S_LEN) && (kk >= q) && (kk <= q + 32);
      float s = ok ? st[kt][rr] * 0.125f : -3.0e38f;
      pv[kt][rr] = s;
      mx = fmaxf(mx, s);
    }
  mx = fmaxf(mx, __shfl_xor(mx, 16, 64));
  mx = fmaxf(mx, __shfl_xor(mx, 32, 64));

  float rsum = 0.f;
#pragma unroll
  for (int kt = 0; kt < 6; ++kt)
#pragma unroll
    for (int rr = 0; rr < 4; ++rr) {
      float p = __expf(pv[kt][rr] - mx);
      pv[kt][rr] = p;
      rsum += p;
    }
  rsum += __shfl_xor(rsum, 16, 64);
  rsum += __shfl_xor(rsum, 32, 64);
  const float inv = 1.0f / rsum;

  // ---- write unnormalized P bf16 into sP = sKP, layout [q][k] stride PST ----
  unsigned short* sP = sKP;
#pragma unroll
  for (int kt = 0; kt < 6; ++kt) {
    ushort4 w = make_ushort4(f2bf(pv[kt][0]), f2bf(pv[kt][1]),
                             f2bf(pv[kt][2]), f2bf(pv[kt][3]));
    *reinterpret_cast<ushort4*>(&sP[(q0 + qc) * PST + kt * 16 + lgrp * 4]) = w;
  }

  // ---- phase 2: ctx^T = V^T @ P^T  (12 MFMA) ----
  bf16x8 pb[3];
#pragma unroll
  for (int ks = 0; ks < 3; ++ks)
    pb[ks] = *reinterpret_cast<const bf16x8*>(
        &sP[(q0 + qc) * PST + ks * 32 + lgrp * 8]);

  f32x4 ct[4] = {};
#pragma unroll
  for (int dt = 0; dt < 4; ++dt)
#pragma unroll
    for (int ks = 0; ks < 3; ++ks) {
      bf16x8 fa = *reinterpret_cast<const bf16x8*>(
          &sVT[(dt * 16 + qc) * PST + ks * 32 + lgrp * 8]);
      ct[dt] = __builtin_amdgcn_mfma_f32_16x16x32_bf16(fa, pb[ks], ct[dt], 0, 0, 0);
    }

  // ---- epilogue ----
  unsigned short* op =
      ctx + ((size_t)b * S_LEN + i0 + q0 + qc) * DMODEL + h * HD;
#pragma unroll
  for (int dt = 0; dt < 4; ++dt) {
    ushort4 w = make_ushort4(
        f2bf(ct[dt][0] * inv), f2bf(ct[dt][1] * inv),
        f2bf(ct[dt][2] * inv), f2bf(ct[dt][3] * inv));
    *reinterpret_cast<ushort4*>(op + dt * 16 + lgrp * 4) = w;
  }
}

// ---------------------------------------------------------------------------
extern "C" void kernel_launch(void* const* d_in, const int* in_sizes, int n_in,
                              void* d_out, int out_size, void* d_ws, size_t ws_size,
                              hipStream_t stream) {
  const float* x     = (const float*)d_in[0];
  const float* w_in  = (const float*)d_in[1];
  const float* b_in  = (const float*)d_in[2];
  const float* w_out = (const float*)d_in[3];
  const float* b_out = (const float*)d_in[4];
  float* out = (float*)d_out;

  // workspace layout (bf16 = ushort), total ~92 MB
  unsigned short* xb   = (unsigned short*)d_ws;
  unsigned short* wib  = xb  + (size_t)8192 * 1024;
  unsigned short* wob  = wib + (size_t)3072 * 1024;
  unsigned short* qkv  = wob + (size_t)1024 * 1024;
  unsigned short* ctxb = qkv + (size_t)8192 * 3072;

  cvt_bf16_kernel<<<8192, 256, 0, stream>>>(x, xb, (8192 * 1024) / 4);
  cvt_bf16_kernel<<<3072, 256, 0, stream>>>(w_in, wib, (3072 * 1024) / 4);
  cvt_bf16_kernel<<<1024, 256, 0, stream>>>(w_out, wob, (1024 * 1024) / 4);

  // QKV = x @ w_in^T + b_in -> [8192, 3072] bf16; grid 32x24=768 (3 exact CU rounds)
  gemm8p_kernel<1><<<768, 512, 0, stream>>>(
      xb, wib, b_in, (void*)qkv, 8192, 3072, 1024, 24);

  // windowed attention -> ctx [8192, 1024] bf16
  attn_local_kernel<<<BATCHN * NH * (S_LEN / 64), 256, 0, stream>>>(qkv, ctxb);

  // out = ctx @ w_out^T + b_out -> [8192, 1024] f32; grid 32x8=256 (1 exact round)
  gemm8p_kernel<0><<<256, 512, 0, stream>>>(
      ctxb, wob, b_out, (void*)out, 8192, 1024, 1024, 8);
}

// Round 6
// 139.154 us; speedup vs baseline: 3.9603x; 1.0077x over previous
//
#include <hip/hip_runtime.h>

// Problem constants
#define S_LEN   1024
#define NH      16
#define HD      64
#define BATCHN  8
#define DMODEL  1024
#define HALF_W  16          // window//2

typedef __attribute__((ext_vector_type(8))) short bf16x8;   // 8 bf16 = 4 VGPRs
typedef __attribute__((ext_vector_type(4))) float f32x4;

__device__ __forceinline__ unsigned short f2bf(float f) {
  unsigned u = __builtin_bit_cast(unsigned, f);
  u += 0x7fffu + ((u >> 16) & 1u);          // round-to-nearest-even
  return (unsigned short)(u >> 16);
}
__device__ __forceinline__ float bf2f(unsigned short h) {
  return __builtin_bit_cast(float, ((unsigned)h) << 16);
}

__device__ __forceinline__ void gload_lds16(const void* g, void* l) {
  __builtin_amdgcn_global_load_lds(
      (const __attribute__((address_space(1))) void*)g,
      (__attribute__((address_space(3))) void*)l, 16, 0, 0);
}

// ---------------------------------------------------------------------------
// f32 -> bf16 conversion (vectorized)
// ---------------------------------------------------------------------------
__global__ __launch_bounds__(256) void cvt_bf16_kernel(
    const float* __restrict__ in, unsigned short* __restrict__ out, int n4) {
  int t = blockIdx.x * 256 + threadIdx.x;
  if (t >= n4) return;
  float4 v = reinterpret_cast<const float4*>(in)[t];
  ushort4 o = make_ushort4(f2bf(v.x), f2bf(v.y), f2bf(v.z), f2bf(v.w));
  reinterpret_cast<ushort4*>(out)[t] = o;
}

// ---------------------------------------------------------------------------
// 256x256 deep-pipelined GEMM: C[M,N] = A[M,1024] * B[N,1024]^T + bias[N]
// 8 waves (2M x 4N), per-wave 128x64. BK=64 as two 32-col kh-slabs.
// Phases per K-tile: (kh0,ch0)(kh0,ch1) | (kh1,ch0)(kh1,ch1), barriers only
// at pair boundaries with counted vmcnt(8) gates. Slab staging:
// t:P12 stages k1[t+1], t:P34 stages k0[t+2]  (4-6 phase prefetch distance).
// LDS 128 KiB (2 buf x 2 kh x 256x32 x 2 arrays).
// ---------------------------------------------------------------------------
#define MFMA_BF16 __builtin_amdgcn_mfma_f32_16x16x32_bf16

#define GATE(NSTR) do {                                                    \
    asm volatile("s_waitcnt vmcnt(" NSTR ")" ::: "memory");                \
    __builtin_amdgcn_sched_barrier(0);                                     \
    __builtin_amdgcn_s_barrier(); } while (0)

#define STAGE_A(KT, BUF, KH) do {                                          \
    gload_lds16(gA_s + (KT) * 64 + (KH) * 32,          &sA[BUF][KH][wid * 512]); \
    gload_lds16(gA_s + 131072 + (KT) * 64 + (KH) * 32, &sA[BUF][KH][wid * 512 + 4096]); } while (0)
#define STAGE_B(KT, BUF, KH) do {                                          \
    gload_lds16(gB_s + (KT) * 64 + (KH) * 32,          &sB[BUF][KH][wid * 512]); \
    gload_lds16(gB_s + 131072 + (KT) * 64 + (KH) * 32, &sB[BUF][KH][wid * 512 + 4096]); } while (0)

#define PH(BUF, KH, CH, STG) do {                                          \
    const unsigned short* _pa = &sA[BUF][KH][arow + (CH) * 2048];          \
    bf16x8 a0_ = *(const bf16x8*)(_pa);                                    \
    bf16x8 a1_ = *(const bf16x8*)(_pa + 512);                              \
    bf16x8 a2_ = *(const bf16x8*)(_pa + 1024);                             \
    bf16x8 a3_ = *(const bf16x8*)(_pa + 1536);                             \
    if ((CH) == 0) {                                                       \
      const unsigned short* _pb = &sB[BUF][KH][brow];                      \
      nb0 = *(const bf16x8*)(_pb);        nb1 = *(const bf16x8*)(_pb + 512);  \
      nb2 = *(const bf16x8*)(_pb + 1024); nb3 = *(const bf16x8*)(_pb + 1536); } \
    STG;                                                                   \
    asm volatile("s_waitcnt lgkmcnt(0)" ::: "memory");                     \
    __builtin_amdgcn_sched_barrier(0);                                     \
    __builtin_amdgcn_s_setprio(1);                                         \
    acc[(CH)*4+0][0] = MFMA_BF16(a0_, nb0, acc[(CH)*4+0][0], 0, 0, 0);     \
    acc[(CH)*4+0][1] = MFMA_BF16(a0_, nb1, acc[(CH)*4+0][1], 0, 0, 0);     \
    acc[(CH)*4+0][2] = MFMA_BF16(a0_, nb2, acc[(CH)*4+0][2], 0, 0, 0);     \
    acc[(CH)*4+0][3] = MFMA_BF16(a0_, nb3, acc[(CH)*4+0][3], 0, 0, 0);     \
    acc[(CH)*4+1][0] = MFMA_BF16(a1_, nb0, acc[(CH)*4+1][0], 0, 0, 0);     \
    acc[(CH)*4+1][1] = MFMA_BF16(a1_, nb1, acc[(CH)*4+1][1], 0, 0, 0);     \
    acc[(CH)*4+1][2] = MFMA_BF16(a1_, nb2, acc[(CH)*4+1][2], 0, 0, 0);     \
    acc[(CH)*4+1][3] = MFMA_BF16(a1_, nb3, acc[(CH)*4+1][3], 0, 0, 0);     \
    acc[(CH)*4+2][0] = MFMA_BF16(a2_, nb0, acc[(CH)*4+2][0], 0, 0, 0);     \
    acc[(CH)*4+2][1] = MFMA_BF16(a2_, nb1, acc[(CH)*4+2][1], 0, 0, 0);     \
    acc[(CH)*4+2][2] = MFMA_BF16(a2_, nb2, acc[(CH)*4+2][2], 0, 0, 0);     \
    acc[(CH)*4+2][3] = MFMA_BF16(a2_, nb3, acc[(CH)*4+2][3], 0, 0, 0);     \
    acc[(CH)*4+3][0] = MFMA_BF16(a3_, nb0, acc[(CH)*4+3][0], 0, 0, 0);     \
    acc[(CH)*4+3][1] = MFMA_BF16(a3_, nb1, acc[(CH)*4+3][1], 0, 0, 0);     \
    acc[(CH)*4+3][2] = MFMA_BF16(a3_, nb2, acc[(CH)*4+3][2], 0, 0, 0);     \
    acc[(CH)*4+3][3] = MFMA_BF16(a3_, nb3, acc[(CH)*4+3][3], 0, 0, 0);     \
    __builtin_amdgcn_s_setprio(0);                                         \
  } while (0)

template <int OUT_BF16>
__global__ __launch_bounds__(512, 2) void gemm256_kernel(
    const unsigned short* __restrict__ A,
    const unsigned short* __restrict__ B,
    const float* __restrict__ bias,
    void* __restrict__ Cv,
    int N, int gy) {
  __shared__ __align__(16) unsigned short sA[2][2][8192];   // [buf][kh][256*32]
  __shared__ __align__(16) unsigned short sB[2][2][8192];

  const int tid  = threadIdx.x;
  const int lane = tid & 63;
  const int wid  = tid >> 6;       // 0..7
  const int wm   = wid >> 2;       // 0..1
  const int wn   = wid & 3;        // 0..3
  const int lgrp = lane >> 4;      // 0..3
  const int l15  = lane & 15;

  // T1: bijective XCD swizzle (grid % 8 == 0)
  const int nwg = gridDim.x;
  const int cpx = nwg >> 3;
  const int sid = (blockIdx.x & 7) * cpx + (blockIdx.x >> 3);
  const int tileM = (sid / gy) * 256;
  const int tileN = (sid % gy) * 256;

  // stage source (pre-swizzled): thread t -> row tid>>2, phys chunk tid&3
  const int srow = tid >> 2;
  const int sk   = tid & 3;
  const int scol = (sk ^ ((srow & 3) ^ ((srow >> 2) & 3))) * 8;
  const unsigned short* gA_s = A + (size_t)(tileM + srow) * 1024 + scol;
  const unsigned short* gB_s = B + (size_t)(tileN + srow) * 1024 + scol;

  // fragment read bases (swizzled)
  const int axr  = lgrp ^ ((l15 & 3) ^ ((l15 >> 2) & 3));
  const int arow = (wm * 128 + l15) * 32 + axr * 8;
  const int brow = (wn * 64  + l15) * 32 + axr * 8;

  f32x4 acc[8][4] = {};
  bf16x8 nb0 = {}, nb1 = {}, nb2 = {}, nb3 = {};

  // prologue: k0[t0], k1[t0], k0[t1]  (12 loads, exact ledger order)
  STAGE_A(0, 0, 0); STAGE_B(0, 0, 0);
  STAGE_A(0, 0, 1); STAGE_B(0, 0, 1);
  STAGE_A(1, 1, 0); STAGE_B(1, 1, 0);

  // main: tiles 0..13 (steady state)
  for (int kt = 0; kt < 14; kt += 2) {
    // tile kt (buf0)
    GATE("8"); PH(0, 0, 0, STAGE_A(kt + 1, 1, 1));
               PH(0, 0, 1, STAGE_B(kt + 1, 1, 1));
    GATE("8"); PH(0, 1, 0, STAGE_A(kt + 2, 0, 0));
               PH(0, 1, 1, STAGE_B(kt + 2, 0, 0));
    // tile kt+1 (buf1)
    GATE("8"); PH(1, 0, 0, STAGE_A(kt + 2, 0, 1));
               PH(1, 0, 1, STAGE_B(kt + 2, 0, 1));
    GATE("8"); PH(1, 1, 0, STAGE_A(kt + 3, 1, 0));
               PH(1, 1, 1, STAGE_B(kt + 3, 1, 0));
  }
  // tile 14 (buf0): stage k1[15] only
  GATE("8"); PH(0, 0, 0, STAGE_A(15, 1, 1));
             PH(0, 0, 1, STAGE_B(15, 1, 1));
  GATE("8"); PH(0, 1, 0, (void)0);
             PH(0, 1, 1, (void)0);
  // tile 15 (buf1): no stages, tail gates
  GATE("4"); PH(1, 0, 0, (void)0);
             PH(1, 0, 1, (void)0);
  GATE("0"); PH(1, 1, 0, (void)0);
             PH(1, 1, 1, (void)0);

  // epilogue: C/D layout col = lane&15 (B-row), row = lgrp*4 + rr (A-row)
#pragma unroll
  for (int nt = 0; nt < 4; ++nt) {
    const int col = tileN + wn * 64 + nt * 16 + l15;
    const float bs = bias[col];
#pragma unroll
    for (int ch = 0; ch < 2; ++ch)
#pragma unroll
      for (int mt = 0; mt < 4; ++mt) {
        const int row0 = tileM + wm * 128 + ch * 64 + mt * 16 + lgrp * 4;
#pragma unroll
        for (int rr = 0; rr < 4; ++rr) {
          float v = acc[ch * 4 + mt][nt][rr] + bs;
          if (OUT_BF16) {
            ((unsigned short*)Cv)[(size_t)(row0 + rr) * N + col] = f2bf(v);
          } else {
            ((float*)Cv)[(size_t)(row0 + rr) * N + col] = v;
          }
        }
      }
  }
}

// ---------------------------------------------------------------------------
// Windowed attention v3 (MFMA). Block = (b, h, 64-query tile), 4 waves.
// ---------------------------------------------------------------------------
#define KST 72    // sK/sQ stride (bf16): 144B rows -> 2-way bank alias (free)
#define PST 104   // sVT/sP stride (bf16): 208B rows -> uniform 2-way

__global__ __launch_bounds__(256) void attn_local_kernel(
    const unsigned short* __restrict__ qkv, unsigned short* __restrict__ ctx) {
  __shared__ __align__(16) unsigned short sKP[96 * KST];   // K, later P
  __shared__ __align__(16) unsigned short sQ[64 * KST];
  __shared__ __align__(16) unsigned short sVT[64 * PST];

  const int tid  = threadIdx.x;
  const int lane = tid & 63;
  const int wid  = tid >> 6;
  const int qc   = lane & 15;        // query col within wave's 16
  const int lgrp = lane >> 4;        // 0..3

  const int qb = blockIdx.x & 15;    // S/64 = 16
  const int h  = (blockIdx.x >> 4) & 15;
  const int b  = blockIdx.x >> 8;
  const int i0 = qb * 64;

  const unsigned short* hb = qkv + (size_t)b * S_LEN * 3072 + (size_t)h * HD;

  // ---- stage K [96][KST] and V^T [64][PST] ----
#pragma unroll
  for (int it = 0; it < 3; ++it) {
    int c  = it * 256 + tid;         // 0..767
    int r  = c >> 3;                 // key row 0..95
    int d0 = (c & 7) * 8;            // dim chunk
    int j  = i0 - 16 + r;
    bf16x8 kv = {}, vv = {};
    if (0 <= j && j < S_LEN) {
      const unsigned short* rp = hb + (size_t)j * 3072;
      kv = *reinterpret_cast<const bf16x8*>(rp + DMODEL + d0);
      vv = *reinterpret_cast<const bf16x8*>(rp + 2 * DMODEL + d0);
    }
    *reinterpret_cast<bf16x8*>(&sKP[r * KST + d0]) = kv;
#pragma unroll
    for (int jj = 0; jj < 8; ++jj) {
      int dd = (jj + c) & 7;
      sVT[(d0 + dd) * PST + r] = (unsigned short)vv[dd];
    }
  }
  // ---- stage Q [64][KST] ----
#pragma unroll
  for (int it = 0; it < 2; ++it) {
    int c  = it * 256 + tid;         // 0..511
    int r  = c >> 3;                 // query row 0..63
    int d0 = (c & 7) * 8;
    bf16x8 qv = *reinterpret_cast<const bf16x8*>(hb + (size_t)(i0 + r) * 3072 + d0);
    *reinterpret_cast<bf16x8*>(&sQ[r * KST + d0]) = qv;
  }
  __syncthreads();

  const int q0 = wid * 16;

  // ---- phase 1: S^T = K @ Q^T  (12 MFMA) ----
  bf16x8 bq[2];
#pragma unroll
  for (int ks = 0; ks < 2; ++ks)
    bq[ks] = *reinterpret_cast<const bf16x8*>(
        &sQ[(q0 + qc) * KST + ks * 32 + lgrp * 8]);

  f32x4 st[6] = {};
#pragma unroll
  for (int kt = 0; kt < 6; ++kt) {
#pragma unroll
    for (int ks = 0; ks < 2; ++ks) {
      bf16x8 fa = *reinterpret_cast<const bf16x8*>(
          &sKP[(kt * 16 + qc) * KST + ks * 32 + lgrp * 8]);
      st[kt] = __builtin_amdgcn_mfma_f32_16x16x32_bf16(fa, bq[ks], st[kt], 0, 0, 0);
    }
  }
  __syncthreads();   // all waves done reading sKP before P overlays it

  // ---- mask + softmax ----
  const int q = q0 + qc;
  float pv[6][4];
  float mx = -3.0e38f;
#pragma unroll
  for (int kt = 0; kt < 6; ++kt)
#pragma unroll
    for (int rr = 0; rr < 4; ++rr) {
      int kk = kt * 16 + lgrp * 4 + rr;     // local key 0..95
      int j  = i0 - 16 + kk;
      bool ok = (j >= 0) && (j < S_LEN) && (kk >= q) && (kk <= q + 32);
      float s = ok ? st[kt][rr] * 0.125f : -3.0e38f;
      pv[kt][rr] = s;
      mx = fmaxf(mx, s);
    }
  mx = fmaxf(mx, __shfl_xor(mx, 16, 64));
  mx = fmaxf(mx, __shfl_xor(mx, 32, 64));

  float rsum = 0.f;
#pragma unroll
  for (int kt = 0; kt < 6; ++kt)
#pragma unroll
    for (int rr = 0; rr < 4; ++rr) {
      float p = __expf(pv[kt][rr] - mx);
      pv[kt][rr] = p;
      rsum += p;
    }
  rsum += __shfl_xor(rsum, 16, 64);
  rsum += __shfl_xor(rsum, 32, 64);
  const float inv = 1.0f / rsum;

  // ---- write unnormalized P bf16 into sP = sKP, layout [q][k] stride PST ----
  unsigned short* sP = sKP;
#pragma unroll
  for (int kt = 0; kt < 6; ++kt) {
    ushort4 w = make_ushort4(f2bf(pv[kt][0]), f2bf(pv[kt][1]),
                             f2bf(pv[kt][2]), f2bf(pv[kt][3]));
    *reinterpret_cast<ushort4*>(&sP[(q0 + qc) * PST + kt * 16 + lgrp * 4]) = w;
  }

  // ---- phase 2: ctx^T = V^T @ P^T  (12 MFMA) ----
  bf16x8 pb[3];
#pragma unroll
  for (int ks = 0; ks < 3; ++ks)
    pb[ks] = *reinterpret_cast<const bf16x8*>(
        &sP[(q0 + qc) * PST + ks * 32 + lgrp * 8]);

  f32x4 ct[4] = {};
#pragma unroll
  for (int dt = 0; dt < 4; ++dt)
#pragma unroll
    for (int ks = 0; ks < 3; ++ks) {
      bf16x8 fa = *reinterpret_cast<const bf16x8*>(
          &sVT[(dt * 16 + qc) * PST + ks * 32 + lgrp * 8]);
      ct[dt] = __builtin_amdgcn_mfma_f32_16x16x32_bf16(fa, pb[ks], ct[dt], 0, 0, 0);
    }

  // ---- epilogue ----
  unsigned short* op =
      ctx + ((size_t)b * S_LEN + i0 + q0 + qc) * DMODEL + h * HD;
#pragma unroll
  for (int dt = 0; dt < 4; ++dt) {
    ushort4 w = make_ushort4(
        f2bf(ct[dt][0] * inv), f2bf(ct[dt][1] * inv),
        f2bf(ct[dt][2] * inv), f2bf(ct[dt][3] * inv));
    *reinterpret_cast<ushort4*>(op + dt * 16 + lgrp * 4) = w;
  }
}

// ---------------------------------------------------------------------------
extern "C" void kernel_launch(void* const* d_in, const int* in_sizes, int n_in,
                              void* d_out, int out_size, void* d_ws, size_t ws_size,
                              hipStream_t stream) {
  const float* x     = (const float*)d_in[0];
  const float* w_in  = (const float*)d_in[1];
  const float* b_in  = (const float*)d_in[2];
  const float* w_out = (const float*)d_in[3];
  const float* b_out = (const float*)d_in[4];
  float* out = (float*)d_out;

  // workspace layout (bf16 = ushort), total ~92 MB
  unsigned short* xb   = (unsigned short*)d_ws;
  unsigned short* wib  = xb  + (size_t)8192 * 1024;
  unsigned short* wob  = wib + (size_t)3072 * 1024;
  unsigned short* qkv  = wob + (size_t)1024 * 1024;
  unsigned short* ctxb = qkv + (size_t)8192 * 3072;

  cvt_bf16_kernel<<<8192, 256, 0, stream>>>(x, xb, (8192 * 1024) / 4);
  cvt_bf16_kernel<<<3072, 256, 0, stream>>>(w_in, wib, (3072 * 1024) / 4);
  cvt_bf16_kernel<<<1024, 256, 0, stream>>>(w_out, wob, (1024 * 1024) / 4);

  // QKV = x @ w_in^T + b_in -> [8192, 3072] bf16; grid 32x12 = 384 (384%8==0)
  gemm256_kernel<1><<<384, 512, 0, stream>>>(
      xb, wib, b_in, (void*)qkv, 3072, 12);

  // windowed attention -> ctx [8192, 1024] bf16
  attn_local_kernel<<<BATCHN * NH * (S_LEN / 64), 256, 0, stream>>>(qkv, ctxb);

  // out = ctx @ w_out^T + b_out -> [8192, 1024] f32; grid 32x4 = 128
  gemm256_kernel<0><<<128, 512, 0, stream>>>(
      ctxb, wob, b_out, (void*)out, 1024, 4);
}

// Round 7
// 132.412 us; speedup vs baseline: 4.1619x; 1.0509x over previous
//
#include <hip/hip_runtime.h>

// Problem constants
#define S_LEN   1024
#define NH      16
#define HD      64
#define BATCHN  8
#define DMODEL  1024
#define HALF_W  16          // window//2

typedef __attribute__((ext_vector_type(8))) short bf16x8;   // 8 bf16 = 4 VGPRs
typedef __attribute__((ext_vector_type(4))) float f32x4;

__device__ __forceinline__ unsigned short f2bf(float f) {
  unsigned u = __builtin_bit_cast(unsigned, f);
  u += 0x7fffu + ((u >> 16) & 1u);          // round-to-nearest-even
  return (unsigned short)(u >> 16);
}
__device__ __forceinline__ float bf2f(unsigned short h) {
  return __builtin_bit_cast(float, ((unsigned)h) << 16);
}

__device__ __forceinline__ void gload_lds16(const void* g, void* l) {
  __builtin_amdgcn_global_load_lds(
      (const __attribute__((address_space(1))) void*)g,
      (__attribute__((address_space(3))) void*)l, 16, 0, 0);
}

// ---------------------------------------------------------------------------
// f32 -> bf16 conversion (vectorized)
// ---------------------------------------------------------------------------
__global__ __launch_bounds__(256) void cvt_bf16_kernel(
    const float* __restrict__ in, unsigned short* __restrict__ out, int n4) {
  int t = blockIdx.x * 256 + threadIdx.x;
  if (t >= n4) return;
  float4 v = reinterpret_cast<const float4*>(in)[t];
  ushort4 o = make_ushort4(f2bf(v.x), f2bf(v.y), f2bf(v.z), f2bf(v.w));
  reinterpret_cast<ushort4*>(out)[t] = o;
}

// ---------------------------------------------------------------------------
// Deep-pipelined GEMM: C[M,N] = A[M,1024] * B[N,1024]^T + bias[N]
// CHN=2: tile 256x256, 8 waves 2Mx4N, per-wave 128x64 (in-proj).
// CHN=1: tile 128x256, 8 waves 2Mx4N, per-wave 64x64  (out-proj, grid 256).
// K staged as 32-col kh-slabs (64B rows -> naturally 2-way-free banking, NO
// swizzle — R6's swizzle was derived for 128B rows and CAUSED 8-way).
// Distance-3 slab prefetch, counted vmcnt gates, raw s_barrier, setprio.
// LDS: CHN2 128 KiB, CHN1 96 KiB.
// ---------------------------------------------------------------------------
#define MFMA_BF16 __builtin_amdgcn_mfma_f32_16x16x32_bf16

template <int OUT_BF16, int CHN>
__global__ __launch_bounds__(512, 2) void gemmdp_kernel(
    const unsigned short* __restrict__ A,
    const unsigned short* __restrict__ B,
    const float* __restrict__ bias,
    void* __restrict__ Cv,
    int N, int gy) {
  __shared__ __align__(16) unsigned short sA[2][2][CHN * 4096];
  __shared__ __align__(16) unsigned short sB[2][2][8192];

  const int tid  = threadIdx.x;
  const int lane = tid & 63;
  const int wid  = tid >> 6;       // 0..7
  const int wm   = wid >> 2;       // 0..1
  const int wn   = wid & 3;        // 0..3
  const int lgrp = lane >> 4;      // 0..3
  const int l15  = lane & 15;

  // T1: bijective XCD swizzle (grid % 8 == 0)
  const int nwg = gridDim.x;
  const int cpx = nwg >> 3;
  const int sid = (blockIdx.x & 7) * cpx + (blockIdx.x >> 3);
  const int tileM = (sid / gy) * (CHN * 128);
  const int tileN = (sid % gy) * 256;

  // stage source: thread t -> row t>>2 (0..127), col chunk (t&3)*8 (linear)
  const int srow = tid >> 2;
  const int scol = (tid & 3) * 8;
  const unsigned short* gA_s = A + (size_t)(tileM + srow) * 1024 + scol;
  const unsigned short* gB_s = B + (size_t)(tileN + srow) * 1024 + scol;

  // fragment read bases (element offsets within a [rows][32] slab)
  const int arow = (wm * (CHN * 64) + l15) * 32 + lgrp * 8;
  const int brow = (wn * 64 + l15) * 32 + lgrp * 8;

  f32x4 acc[CHN * 4][4] = {};
  bf16x8 nb0 = {}, nb1 = {}, nb2 = {}, nb3 = {};

#define SSA(KT, BUF, KH) do {                                              \
    const unsigned short* _sa = gA_s + (KT) * 64 + (KH) * 32;              \
    gload_lds16(_sa, &sA[BUF][KH][wid * 512]);                             \
    if constexpr (CHN == 2)                                                \
      gload_lds16(_sa + 131072, &sA[BUF][KH][4096 + wid * 512]);           \
  } while (0)
#define SSB(KT, BUF, KH) do {                                              \
    const unsigned short* _sb = gB_s + (KT) * 64 + (KH) * 32;              \
    gload_lds16(_sb, &sB[BUF][KH][wid * 512]);                             \
    gload_lds16(_sb + 131072, &sB[BUF][KH][4096 + wid * 512]);             \
  } while (0)

#define GATE_S do {                                                        \
    if constexpr (CHN == 2) asm volatile("s_waitcnt vmcnt(8)" ::: "memory");\
    else                    asm volatile("s_waitcnt vmcnt(6)" ::: "memory");\
    __builtin_amdgcn_sched_barrier(0);                                     \
    __builtin_amdgcn_s_barrier(); } while (0)
#define GATE_H do {                                                        \
    if constexpr (CHN == 2) asm volatile("s_waitcnt vmcnt(4)" ::: "memory");\
    else                    asm volatile("s_waitcnt vmcnt(3)" ::: "memory");\
    __builtin_amdgcn_sched_barrier(0);                                     \
    __builtin_amdgcn_s_barrier(); } while (0)
#define GATE_Z do {                                                        \
    asm volatile("s_waitcnt vmcnt(0)" ::: "memory");                       \
    __builtin_amdgcn_sched_barrier(0);                                     \
    __builtin_amdgcn_s_barrier(); } while (0)

#define PH(BUF, KH, CH, STG) do {                                          \
    const unsigned short* _pa = &sA[BUF][KH][arow + (CH) * 2048];          \
    bf16x8 a0_ = *(const bf16x8*)(_pa);                                    \
    bf16x8 a1_ = *(const bf16x8*)(_pa + 512);                              \
    bf16x8 a2_ = *(const bf16x8*)(_pa + 1024);                             \
    bf16x8 a3_ = *(const bf16x8*)(_pa + 1536);                             \
    if ((CH) == 0) {                                                       \
      const unsigned short* _pb = &sB[BUF][KH][brow];                      \
      nb0 = *(const bf16x8*)(_pb);        nb1 = *(const bf16x8*)(_pb + 512);  \
      nb2 = *(const bf16x8*)(_pb + 1024); nb3 = *(const bf16x8*)(_pb + 1536); } \
    STG;                                                                   \
    asm volatile("s_waitcnt lgkmcnt(0)" ::: "memory");                     \
    __builtin_amdgcn_sched_barrier(0);                                     \
    __builtin_amdgcn_s_setprio(1);                                         \
    acc[(CH)*4+0][0] = MFMA_BF16(a0_, nb0, acc[(CH)*4+0][0], 0, 0, 0);     \
    acc[(CH)*4+0][1] = MFMA_BF16(a0_, nb1, acc[(CH)*4+0][1], 0, 0, 0);     \
    acc[(CH)*4+0][2] = MFMA_BF16(a0_, nb2, acc[(CH)*4+0][2], 0, 0, 0);     \
    acc[(CH)*4+0][3] = MFMA_BF16(a0_, nb3, acc[(CH)*4+0][3], 0, 0, 0);     \
    acc[(CH)*4+1][0] = MFMA_BF16(a1_, nb0, acc[(CH)*4+1][0], 0, 0, 0);     \
    acc[(CH)*4+1][1] = MFMA_BF16(a1_, nb1, acc[(CH)*4+1][1], 0, 0, 0);     \
    acc[(CH)*4+1][2] = MFMA_BF16(a1_, nb2, acc[(CH)*4+1][2], 0, 0, 0);     \
    acc[(CH)*4+1][3] = MFMA_BF16(a1_, nb3, acc[(CH)*4+1][3], 0, 0, 0);     \
    acc[(CH)*4+2][0] = MFMA_BF16(a2_, nb0, acc[(CH)*4+2][0], 0, 0, 0);     \
    acc[(CH)*4+2][1] = MFMA_BF16(a2_, nb1, acc[(CH)*4+2][1], 0, 0, 0);     \
    acc[(CH)*4+2][2] = MFMA_BF16(a2_, nb2, acc[(CH)*4+2][2], 0, 0, 0);     \
    acc[(CH)*4+2][3] = MFMA_BF16(a2_, nb3, acc[(CH)*4+2][3], 0, 0, 0);     \
    acc[(CH)*4+3][0] = MFMA_BF16(a3_, nb0, acc[(CH)*4+3][0], 0, 0, 0);     \
    acc[(CH)*4+3][1] = MFMA_BF16(a3_, nb1, acc[(CH)*4+3][1], 0, 0, 0);     \
    acc[(CH)*4+3][2] = MFMA_BF16(a3_, nb2, acc[(CH)*4+3][2], 0, 0, 0);     \
    acc[(CH)*4+3][3] = MFMA_BF16(a3_, nb3, acc[(CH)*4+3][3], 0, 0, 0);     \
    __builtin_amdgcn_s_setprio(0);                                         \
  } while (0)

#define DOPAIR(BUF, KH, STGA, STGB) do {                                   \
    if constexpr (CHN == 2) {                                              \
      PH(BUF, KH, 0, STGA);                                                \
      PH(BUF, KH, 1, STGB);                                                \
    } else {                                                               \
      PH(BUF, KH, 0, do { STGA; STGB; } while (0));                        \
    } } while (0)
#define NOSTG ((void)0)

  // prologue: stage slabs 0,1,2 (slab = (kt,kh) A+B)
  SSA(0, 0, 0); SSB(0, 0, 0);
  SSA(0, 0, 1); SSB(0, 0, 1);
  SSA(1, 1, 0); SSB(1, 1, 0);

  // steady: pairs s = 0..27 (tiles 0..13); pair s stages slab s+3
#pragma unroll 1
  for (int kt = 0; kt < 14; kt += 2) {
    GATE_S; DOPAIR(0, 0, SSA(kt + 1, 1, 1), SSB(kt + 1, 1, 1));
    GATE_S; DOPAIR(0, 1, SSA(kt + 2, 0, 0), SSB(kt + 2, 0, 0));
    GATE_S; DOPAIR(1, 0, SSA(kt + 2, 0, 1), SSB(kt + 2, 0, 1));
    GATE_S; DOPAIR(1, 1, SSA(kt + 3, 1, 0), SSB(kt + 3, 1, 0));
  }
  // tail: tiles 14 (buf0) and 15 (buf1)
  GATE_S; DOPAIR(0, 0, SSA(15, 1, 1), SSB(15, 1, 1));
  GATE_S; DOPAIR(0, 1, NOSTG, NOSTG);
  GATE_H; DOPAIR(1, 0, NOSTG, NOSTG);
  GATE_Z; DOPAIR(1, 1, NOSTG, NOSTG);

#undef SSA
#undef SSB
#undef GATE_S
#undef GATE_H
#undef GATE_Z
#undef PH
#undef DOPAIR
#undef NOSTG

  // epilogue: C/D layout col = lane&15 (B-row), row = lgrp*4 + rr (A-row)
#pragma unroll
  for (int nt = 0; nt < 4; ++nt) {
    const int col = tileN + wn * 64 + nt * 16 + l15;
    const float bs = bias[col];
#pragma unroll
    for (int ch = 0; ch < CHN; ++ch)
#pragma unroll
      for (int mt = 0; mt < 4; ++mt) {
        const int row0 = tileM + wm * (CHN * 64) + ch * 64 + mt * 16 + lgrp * 4;
#pragma unroll
        for (int rr = 0; rr < 4; ++rr) {
          float v = acc[ch * 4 + mt][nt][rr] + bs;
          if (OUT_BF16) {
            ((unsigned short*)Cv)[(size_t)(row0 + rr) * N + col] = f2bf(v);
          } else {
            ((float*)Cv)[(size_t)(row0 + rr) * N + col] = v;
          }
        }
      }
  }
}

// ---------------------------------------------------------------------------
// Windowed attention v3 (MFMA). Block = (b, h, 64-query tile), 4 waves.
// ---------------------------------------------------------------------------
#define KST 72    // sK/sQ stride (bf16): 144B rows -> 2-way bank alias (free)
#define PST 104   // sVT/sP stride (bf16): 208B rows -> uniform 2-way

__global__ __launch_bounds__(256) void attn_local_kernel(
    const unsigned short* __restrict__ qkv, unsigned short* __restrict__ ctx) {
  __shared__ __align__(16) unsigned short sKP[96 * KST];   // K, later P
  __shared__ __align__(16) unsigned short sQ[64 * KST];
  __shared__ __align__(16) unsigned short sVT[64 * PST];

  const int tid  = threadIdx.x;
  const int lane = tid & 63;
  const int wid  = tid >> 6;
  const int qc   = lane & 15;        // query col within wave's 16
  const int lgrp = lane >> 4;        // 0..3

  const int qb = blockIdx.x & 15;    // S/64 = 16
  const int h  = (blockIdx.x >> 4) & 15;
  const int b  = blockIdx.x >> 8;
  const int i0 = qb * 64;

  const unsigned short* hb = qkv + (size_t)b * S_LEN * 3072 + (size_t)h * HD;

  // ---- stage K [96][KST] and V^T [64][PST] ----
#pragma unroll
  for (int it = 0; it < 3; ++it) {
    int c  = it * 256 + tid;         // 0..767
    int r  = c >> 3;                 // key row 0..95
    int d0 = (c & 7) * 8;            // dim chunk
    int j  = i0 - 16 + r;
    bf16x8 kv = {}, vv = {};
    if (0 <= j && j < S_LEN) {
      const unsigned short* rp = hb + (size_t)j * 3072;
      kv = *reinterpret_cast<const bf16x8*>(rp + DMODEL + d0);
      vv = *reinterpret_cast<const bf16x8*>(rp + 2 * DMODEL + d0);
    }
    *reinterpret_cast<bf16x8*>(&sKP[r * KST + d0]) = kv;
#pragma unroll
    for (int jj = 0; jj < 8; ++jj) {
      int dd = (jj + c) & 7;
      sVT[(d0 + dd) * PST + r] = (unsigned short)vv[dd];
    }
  }
  // ---- stage Q [64][KST] ----
#pragma unroll
  for (int it = 0; it < 2; ++it) {
    int c  = it * 256 + tid;         // 0..511
    int r  = c >> 3;                 // query row 0..63
    int d0 = (c & 7) * 8;
    bf16x8 qv = *reinterpret_cast<const bf16x8*>(hb + (size_t)(i0 + r) * 3072 + d0);
    *reinterpret_cast<bf16x8*>(&sQ[r * KST + d0]) = qv;
  }
  __syncthreads();

  const int q0 = wid * 16;

  // ---- phase 1: S^T = K @ Q^T  (12 MFMA) ----
  bf16x8 bq[2];
#pragma unroll
  for (int ks = 0; ks < 2; ++ks)
    bq[ks] = *reinterpret_cast<const bf16x8*>(
        &sQ[(q0 + qc) * KST + ks * 32 + lgrp * 8]);

  f32x4 st[6] = {};
#pragma unroll
  for (int kt = 0; kt < 6; ++kt) {
#pragma unroll
    for (int ks = 0; ks < 2; ++ks) {
      bf16x8 fa = *reinterpret_cast<const bf16x8*>(
          &sKP[(kt * 16 + qc) * KST + ks * 32 + lgrp * 8]);
      st[kt] = __builtin_amdgcn_mfma_f32_16x16x32_bf16(fa, bq[ks], st[kt], 0, 0, 0);
    }
  }
  __syncthreads();   // all waves done reading sKP before P overlays it

  // ---- mask + softmax ----
  const int q = q0 + qc;
  float pv[6][4];
  float mx = -3.0e38f;
#pragma unroll
  for (int kt = 0; kt < 6; ++kt)
#pragma unroll
    for (int rr = 0; rr < 4; ++rr) {
      int kk = kt * 16 + lgrp * 4 + rr;     // local key 0..95
      int j  = i0 - 16 + kk;
      bool ok = (j >= 0) && (j < S_LEN) && (kk >= q) && (kk <= q + 32);
      float s = ok ? st[kt][rr] * 0.125f : -3.0e38f;
      pv[kt][rr] = s;
      mx = fmaxf(mx, s);
    }
  mx = fmaxf(mx, __shfl_xor(mx, 16, 64));
  mx = fmaxf(mx, __shfl_xor(mx, 32, 64));

  float rsum = 0.f;
#pragma unroll
  for (int kt = 0; kt < 6; ++kt)
#pragma unroll
    for (int rr = 0; rr < 4; ++rr) {
      float p = __expf(pv[kt][rr] - mx);
      pv[kt][rr] = p;
      rsum += p;
    }
  rsum += __shfl_xor(rsum, 16, 64);
  rsum += __shfl_xor(rsum, 32, 64);
  const float inv = 1.0f / rsum;

  // ---- write unnormalized P bf16 into sP = sKP, layout [q][k] stride PST ----
  unsigned short* sP = sKP;
#pragma unroll
  for (int kt = 0; kt < 6; ++kt) {
    ushort4 w = make_ushort4(f2bf(pv[kt][0]), f2bf(pv[kt][1]),
                             f2bf(pv[kt][2]), f2bf(pv[kt][3]));
    *reinterpret_cast<ushort4*>(&sP[(q0 + qc) * PST + kt * 16 + lgrp * 4]) = w;
  }

  // ---- phase 2: ctx^T = V^T @ P^T  (12 MFMA) ----
  bf16x8 pb[3];
#pragma unroll
  for (int ks = 0; ks < 3; ++ks)
    pb[ks] = *reinterpret_cast<const bf16x8*>(
        &sP[(q0 + qc) * PST + ks * 32 + lgrp * 8]);

  f32x4 ct[4] = {};
#pragma unroll
  for (int dt = 0; dt < 4; ++dt)
#pragma unroll
    for (int ks = 0; ks < 3; ++ks) {
      bf16x8 fa = *reinterpret_cast<const bf16x8*>(
          &sVT[(dt * 16 + qc) * PST + ks * 32 + lgrp * 8]);
      ct[dt] = __builtin_amdgcn_mfma_f32_16x16x32_bf16(fa, pb[ks], ct[dt], 0, 0, 0);
    }

  // ---- epilogue ----
  unsigned short* op =
      ctx + ((size_t)b * S_LEN + i0 + q0 + qc) * DMODEL + h * HD;
#pragma unroll
  for (int dt = 0; dt < 4; ++dt) {
    ushort4 w = make_ushort4(
        f2bf(ct[dt][0] * inv), f2bf(ct[dt][1] * inv),
        f2bf(ct[dt][2] * inv), f2bf(ct[dt][3] * inv));
    *reinterpret_cast<ushort4*>(op + dt * 16 + lgrp * 4) = w;
  }
}

// ---------------------------------------------------------------------------
extern "C" void kernel_launch(void* const* d_in, const int* in_sizes, int n_in,
                              void* d_out, int out_size, void* d_ws, size_t ws_size,
                              hipStream_t stream) {
  const float* x     = (const float*)d_in[0];
  const float* w_in  = (const float*)d_in[1];
  const float* b_in  = (const float*)d_in[2];
  const float* w_out = (const float*)d_in[3];
  const float* b_out = (const float*)d_in[4];
  float* out = (float*)d_out;

  // workspace layout (bf16 = ushort), total ~92 MB
  unsigned short* xb   = (unsigned short*)d_ws;
  unsigned short* wib  = xb  + (size_t)8192 * 1024;
  unsigned short* wob  = wib + (size_t)3072 * 1024;
  unsigned short* qkv  = wob + (size_t)1024 * 1024;
  unsigned short* ctxb = qkv + (size_t)8192 * 3072;

  cvt_bf16_kernel<<<8192, 256, 0, stream>>>(x, xb, (8192 * 1024) / 4);
  cvt_bf16_kernel<<<3072, 256, 0, stream>>>(w_in, wib, (3072 * 1024) / 4);
  cvt_bf16_kernel<<<1024, 256, 0, stream>>>(w_out, wob, (1024 * 1024) / 4);

  // QKV = x @ w_in^T + b_in -> [8192, 3072] bf16; 256x256 tiles, grid 32x12
  gemmdp_kernel<1, 2><<<384, 512, 0, stream>>>(
      xb, wib, b_in, (void*)qkv, 3072, 12);

  // windowed attention -> ctx [8192, 1024] bf16
  attn_local_kernel<<<BATCHN * NH * (S_LEN / 64), 256, 0, stream>>>(qkv, ctxb);

  // out = ctx @ w_out^T + b_out -> [8192, 1024] f32; 128x256 tiles, grid 64x4=256
  gemmdp_kernel<0, 1><<<256, 512, 0, stream>>>(
      ctxb, wob, b_out, (void*)out, 1024, 4);
}

// Round 8
// 128.340 us; speedup vs baseline: 4.2940x; 1.0317x over previous
//
#include <hip/hip_runtime.h>

// Problem constants
#define S_LEN   1024
#define NH      16
#define HD      64
#define BATCHN  8
#define DMODEL  1024
#define HALF_W  16          // window//2

typedef __attribute__((ext_vector_type(8))) short bf16x8;   // 8 bf16 = 4 VGPRs
typedef __attribute__((ext_vector_type(4))) float f32x4;

__device__ __forceinline__ unsigned short f2bf(float f) {
  unsigned u = __builtin_bit_cast(unsigned, f);
  u += 0x7fffu + ((u >> 16) & 1u);          // round-to-nearest-even
  return (unsigned short)(u >> 16);
}
__device__ __forceinline__ float bf2f(unsigned short h) {
  return __builtin_bit_cast(float, ((unsigned)h) << 16);
}

__device__ __forceinline__ void gload_lds16(const void* g, void* l) {
  __builtin_amdgcn_global_load_lds(
      (const __attribute__((address_space(1))) void*)g,
      (__attribute__((address_space(3))) void*)l, 16, 0, 0);
}

// ---------------------------------------------------------------------------
// f32 -> bf16 conversion (vectorized)
// ---------------------------------------------------------------------------
__global__ __launch_bounds__(256) void cvt_bf16_kernel(
    const float* __restrict__ in, unsigned short* __restrict__ out, int n4) {
  int t = blockIdx.x * 256 + threadIdx.x;
  if (t >= n4) return;
  float4 v = reinterpret_cast<const float4*>(in)[t];
  ushort4 o = make_ushort4(f2bf(v.x), f2bf(v.y), f2bf(v.z), f2bf(v.w));
  reinterpret_cast<ushort4*>(out)[t] = o;
}

// ---------------------------------------------------------------------------
// Deep-pipelined GEMM: C[M,N] = A[M,1024] * B[N,1024]^T + bias[N]
// CHN=2: tile 256x256, 8 waves 2Mx4N, per-wave 128x64 (in-proj).
// CHN=1: tile 128x256, 8 waves 2Mx4N, per-wave 64x64  (out-proj, grid 256).
// K staged as 32-col kh-slabs (64B rows). Bank fix (R8): 64B rows give
// bank-start 16*l15+4*chunk mod 32 -> only 2 positions -> 8-way conflict.
// Swizzle chunk' = chunk ^ ((row>>1)&3): each lgrp group hits all 8 four-bank
// positions 2-way (free). Applied as inverse-swizzled global SOURCE + linear
// gload_lds dest + swizzled ds_read (rule: both-sides-or-neither).
// Distance-3 slab prefetch, counted vmcnt gates, raw s_barrier, setprio.
// ---------------------------------------------------------------------------
#define MFMA_BF16 __builtin_amdgcn_mfma_f32_16x16x32_bf16

template <int OUT_BF16, int CHN>
__global__ __launch_bounds__(512, 2) void gemmdp_kernel(
    const unsigned short* __restrict__ A,
    const unsigned short* __restrict__ B,
    const float* __restrict__ bias,
    void* __restrict__ Cv,
    int N, int gy) {
  __shared__ __align__(16) unsigned short sA[2][2][CHN * 4096];
  __shared__ __align__(16) unsigned short sB[2][2][8192];

  const int tid  = threadIdx.x;
  const int lane = tid & 63;
  const int wid  = tid >> 6;       // 0..7
  const int wm   = wid >> 2;       // 0..1
  const int wn   = wid & 3;        // 0..3
  const int lgrp = lane >> 4;      // 0..3
  const int l15  = lane & 15;

  // T1: bijective XCD swizzle (grid % 8 == 0)
  const int nwg = gridDim.x;
  const int cpx = nwg >> 3;
  const int sid = (blockIdx.x & 7) * cpx + (blockIdx.x >> 3);
  const int tileM = (sid / gy) * (CHN * 128);
  const int tileN = (sid % gy) * 256;

  // stage source: thread t -> slab row t>>2 (0..127), chunk t&3.
  // SOURCE col chunk pre-swizzled by f(row) = (row>>1)&3 = (t>>3)&3.
  const int srow = tid >> 2;
  const int scol = ((tid & 3) ^ ((tid >> 3) & 3)) * 8;
  const unsigned short* gA_s = A + (size_t)(tileM + srow) * 1024 + scol;
  const unsigned short* gB_s = B + (size_t)(tileN + srow) * 1024 + scol;

  // fragment read bases: row = (wgrp*64..) + l15, chunk = lgrp ^ f(row),
  // f(row) = (row>>1)&3 = (l15>>1)&3 (all row offsets are multiples of 8).
  const int fch  = (lgrp ^ ((l15 >> 1) & 3)) * 8;
  const int arow = (wm * (CHN * 64) + l15) * 32 + fch;
  const int brow = (wn * 64 + l15) * 32 + fch;

  f32x4 acc[CHN * 4][4] = {};
  bf16x8 nb0 = {}, nb1 = {}, nb2 = {}, nb3 = {};

#define SSA(KT, BUF, KH) do {                                              \
    const unsigned short* _sa = gA_s + (KT) * 64 + (KH) * 32;              \
    gload_lds16(_sa, &sA[BUF][KH][wid * 512]);                             \
    if constexpr (CHN == 2)                                                \
      gload_lds16(_sa + 131072, &sA[BUF][KH][4096 + wid * 512]);           \
  } while (0)
#define SSB(KT, BUF, KH) do {                                              \
    const unsigned short* _sb = gB_s + (KT) * 64 + (KH) * 32;              \
    gload_lds16(_sb, &sB[BUF][KH][wid * 512]);                             \
    gload_lds16(_sb + 131072, &sB[BUF][KH][4096 + wid * 512]);             \
  } while (0)

#define GATE_S do {                                                        \
    if constexpr (CHN == 2) asm volatile("s_waitcnt vmcnt(8)" ::: "memory");\
    else                    asm volatile("s_waitcnt vmcnt(6)" ::: "memory");\
    __builtin_amdgcn_sched_barrier(0);                                     \
    __builtin_amdgcn_s_barrier(); } while (0)
#define GATE_H do {                                                        \
    if constexpr (CHN == 2) asm volatile("s_waitcnt vmcnt(4)" ::: "memory");\
    else                    asm volatile("s_waitcnt vmcnt(3)" ::: "memory");\
    __builtin_amdgcn_sched_barrier(0);                                     \
    __builtin_amdgcn_s_barrier(); } while (0)
#define GATE_Z do {                                                        \
    asm volatile("s_waitcnt vmcnt(0)" ::: "memory");                       \
    __builtin_amdgcn_sched_barrier(0);                                     \
    __builtin_amdgcn_s_barrier(); } while (0)

#define PH(BUF, KH, CH, STG) do {                                          \
    const unsigned short* _pa = &sA[BUF][KH][arow + (CH) * 2048];          \
    bf16x8 a0_ = *(const bf16x8*)(_pa);                                    \
    bf16x8 a1_ = *(const bf16x8*)(_pa + 512);                              \
    bf16x8 a2_ = *(const bf16x8*)(_pa + 1024);                             \
    bf16x8 a3_ = *(const bf16x8*)(_pa + 1536);                             \
    if ((CH) == 0) {                                                       \
      const unsigned short* _pb = &sB[BUF][KH][brow];                      \
      nb0 = *(const bf16x8*)(_pb);        nb1 = *(const bf16x8*)(_pb + 512);  \
      nb2 = *(const bf16x8*)(_pb + 1024); nb3 = *(const bf16x8*)(_pb + 1536); } \
    STG;                                                                   \
    asm volatile("s_waitcnt lgkmcnt(0)" ::: "memory");                     \
    __builtin_amdgcn_sched_barrier(0);                                     \
    __builtin_amdgcn_s_setprio(1);                                         \
    acc[(CH)*4+0][0] = MFMA_BF16(a0_, nb0, acc[(CH)*4+0][0], 0, 0, 0);     \
    acc[(CH)*4+0][1] = MFMA_BF16(a0_, nb1, acc[(CH)*4+0][1], 0, 0, 0);     \
    acc[(CH)*4+0][2] = MFMA_BF16(a0_, nb2, acc[(CH)*4+0][2], 0, 0, 0);     \
    acc[(CH)*4+0][3] = MFMA_BF16(a0_, nb3, acc[(CH)*4+0][3], 0, 0, 0);     \
    acc[(CH)*4+1][0] = MFMA_BF16(a1_, nb0, acc[(CH)*4+1][0], 0, 0, 0);     \
    acc[(CH)*4+1][1] = MFMA_BF16(a1_, nb1, acc[(CH)*4+1][1], 0, 0, 0);     \
    acc[(CH)*4+1][2] = MFMA_BF16(a1_, nb2, acc[(CH)*4+1][2], 0, 0, 0);     \
    acc[(CH)*4+1][3] = MFMA_BF16(a1_, nb3, acc[(CH)*4+1][3], 0, 0, 0);     \
    acc[(CH)*4+2][0] = MFMA_BF16(a2_, nb0, acc[(CH)*4+2][0], 0, 0, 0);     \
    acc[(CH)*4+2][1] = MFMA_BF16(a2_, nb1, acc[(CH)*4+2][1], 0, 0, 0);     \
    acc[(CH)*4+2][2] = MFMA_BF16(a2_, nb2, acc[(CH)*4+2][2], 0, 0, 0);     \
    acc[(CH)*4+2][3] = MFMA_BF16(a2_, nb3, acc[(CH)*4+2][3], 0, 0, 0);     \
    acc[(CH)*4+3][0] = MFMA_BF16(a3_, nb0, acc[(CH)*4+3][0], 0, 0, 0);     \
    acc[(CH)*4+3][1] = MFMA_BF16(a3_, nb1, acc[(CH)*4+3][1], 0, 0, 0);     \
    acc[(CH)*4+3][2] = MFMA_BF16(a3_, nb2, acc[(CH)*4+3][2], 0, 0, 0);     \
    acc[(CH)*4+3][3] = MFMA_BF16(a3_, nb3, acc[(CH)*4+3][3], 0, 0, 0);     \
    __builtin_amdgcn_s_setprio(0);                                         \
  } while (0)

#define DOPAIR(BUF, KH, STGA, STGB) do {                                   \
    if constexpr (CHN == 2) {                                              \
      PH(BUF, KH, 0, STGA);                                                \
      PH(BUF, KH, 1, STGB);                                                \
    } else {                                                               \
      PH(BUF, KH, 0, do { STGA; STGB; } while (0));                        \
    } } while (0)
#define NOSTG ((void)0)

  // prologue: stage slabs 0,1,2 (slab = (kt,kh) A+B)
  SSA(0, 0, 0); SSB(0, 0, 0);
  SSA(0, 0, 1); SSB(0, 0, 1);
  SSA(1, 1, 0); SSB(1, 1, 0);

  // steady: pairs s = 0..27 (tiles 0..13); pair s stages slab s+3
#pragma unroll 1
  for (int kt = 0; kt < 14; kt += 2) {
    GATE_S; DOPAIR(0, 0, SSA(kt + 1, 1, 1), SSB(kt + 1, 1, 1));
    GATE_S; DOPAIR(0, 1, SSA(kt + 2, 0, 0), SSB(kt + 2, 0, 0));
    GATE_S; DOPAIR(1, 0, SSA(kt + 2, 0, 1), SSB(kt + 2, 0, 1));
    GATE_S; DOPAIR(1, 1, SSA(kt + 3, 1, 0), SSB(kt + 3, 1, 0));
  }
  // tail: tiles 14 (buf0) and 15 (buf1)
  GATE_S; DOPAIR(0, 0, SSA(15, 1, 1), SSB(15, 1, 1));
  GATE_S; DOPAIR(0, 1, NOSTG, NOSTG);
  GATE_H; DOPAIR(1, 0, NOSTG, NOSTG);
  GATE_Z; DOPAIR(1, 1, NOSTG, NOSTG);

#undef SSA
#undef SSB
#undef GATE_S
#undef GATE_H
#undef GATE_Z
#undef PH
#undef DOPAIR
#undef NOSTG

  // epilogue: C/D layout col = lane&15 (B-row), row = lgrp*4 + rr (A-row)
#pragma unroll
  for (int nt = 0; nt < 4; ++nt) {
    const int col = tileN + wn * 64 + nt * 16 + l15;
    const float bs = bias[col];
#pragma unroll
    for (int ch = 0; ch < CHN; ++ch)
#pragma unroll
      for (int mt = 0; mt < 4; ++mt) {
        const int row0 = tileM + wm * (CHN * 64) + ch * 64 + mt * 16 + lgrp * 4;
#pragma unroll
        for (int rr = 0; rr < 4; ++rr) {
          float v = acc[ch * 4 + mt][nt][rr] + bs;
          if (OUT_BF16) {
            ((unsigned short*)Cv)[(size_t)(row0 + rr) * N + col] = f2bf(v);
          } else {
            ((float*)Cv)[(size_t)(row0 + rr) * N + col] = v;
          }
        }
      }
  }
}

// ---------------------------------------------------------------------------
// Windowed attention v3 (MFMA). Block = (b, h, 64-query tile), 4 waves.
// ---------------------------------------------------------------------------
#define KST 72    // sK/sQ stride (bf16): 144B rows -> 2-way bank alias (free)
#define PST 104   // sVT/sP stride (bf16): 208B rows -> uniform 2-way

__global__ __launch_bounds__(256) void attn_local_kernel(
    const unsigned short* __restrict__ qkv, unsigned short* __restrict__ ctx) {
  __shared__ __align__(16) unsigned short sKP[96 * KST];   // K, later P
  __shared__ __align__(16) unsigned short sQ[64 * KST];
  __shared__ __align__(16) unsigned short sVT[64 * PST];

  const int tid  = threadIdx.x;
  const int lane = tid & 63;
  const int wid  = tid >> 6;
  const int qc   = lane & 15;        // query col within wave's 16
  const int lgrp = lane >> 4;        // 0..3

  const int qb = blockIdx.x & 15;    // S/64 = 16
  const int h  = (blockIdx.x >> 4) & 15;
  const int b  = blockIdx.x >> 8;
  const int i0 = qb * 64;

  const unsigned short* hb = qkv + (size_t)b * S_LEN * 3072 + (size_t)h * HD;

  // ---- stage K [96][KST] and V^T [64][PST] ----
#pragma unroll
  for (int it = 0; it < 3; ++it) {
    int c  = it * 256 + tid;         // 0..767
    int r  = c >> 3;                 // key row 0..95
    int d0 = (c & 7) * 8;            // dim chunk
    int j  = i0 - 16 + r;
    bf16x8 kv = {}, vv = {};
    if (0 <= j && j < S_LEN) {
      const unsigned short* rp = hb + (size_t)j * 3072;
      kv = *reinterpret_cast<const bf16x8*>(rp + DMODEL + d0);
      vv = *reinterpret_cast<const bf16x8*>(rp + 2 * DMODEL + d0);
    }
    *reinterpret_cast<bf16x8*>(&sKP[r * KST + d0]) = kv;
#pragma unroll
    for (int jj = 0; jj < 8; ++jj) {
      int dd = (jj + c) & 7;
      sVT[(d0 + dd) * PST + r] = (unsigned short)vv[dd];
    }
  }
  // ---- stage Q [64][KST] ----
#pragma unroll
  for (int it = 0; it < 2; ++it) {
    int c  = it * 256 + tid;         // 0..511
    int r  = c >> 3;                 // query row 0..63
    int d0 = (c & 7) * 8;
    bf16x8 qv = *reinterpret_cast<const bf16x8*>(hb + (size_t)(i0 + r) * 3072 + d0);
    *reinterpret_cast<bf16x8*>(&sQ[r * KST + d0]) = qv;
  }
  __syncthreads();

  const int q0 = wid * 16;

  // ---- phase 1: S^T = K @ Q^T  (12 MFMA) ----
  bf16x8 bq[2];
#pragma unroll
  for (int ks = 0; ks < 2; ++ks)
    bq[ks] = *reinterpret_cast<const bf16x8*>(
        &sQ[(q0 + qc) * KST + ks * 32 + lgrp * 8]);

  f32x4 st[6] = {};
#pragma unroll
  for (int kt = 0; kt < 6; ++kt) {
#pragma unroll
    for (int ks = 0; ks < 2; ++ks) {
      bf16x8 fa = *reinterpret_cast<const bf16x8*>(
          &sKP[(kt * 16 + qc) * KST + ks * 32 + lgrp * 8]);
      st[kt] = __builtin_amdgcn_mfma_f32_16x16x32_bf16(fa, bq[ks], st[kt], 0, 0, 0);
    }
  }
  __syncthreads();   // all waves done reading sKP before P overlays it

  // ---- mask + softmax ----
  const int q = q0 + qc;
  float pv[6][4];
  float mx = -3.0e38f;
#pragma unroll
  for (int kt = 0; kt < 6; ++kt)
#pragma unroll
    for (int rr = 0; rr < 4; ++rr) {
      int kk = kt * 16 + lgrp * 4 + rr;     // local key 0..95
      int j  = i0 - 16 + kk;
      bool ok = (j >= 0) && (j < S_LEN) && (kk >= q) && (kk <= q + 32);
      float s = ok ? st[kt][rr] * 0.125f : -3.0e38f;
      pv[kt][rr] = s;
      mx = fmaxf(mx, s);
    }
  mx = fmaxf(mx, __shfl_xor(mx, 16, 64));
  mx = fmaxf(mx, __shfl_xor(mx, 32, 64));

  float rsum = 0.f;
#pragma unroll
  for (int kt = 0; kt < 6; ++kt)
#pragma unroll
    for (int rr = 0; rr < 4; ++rr) {
      float p = __expf(pv[kt][rr] - mx);
      pv[kt][rr] = p;
      rsum += p;
    }
  rsum += __shfl_xor(rsum, 16, 64);
  rsum += __shfl_xor(rsum, 32, 64);
  const float inv = 1.0f / rsum;

  // ---- write unnormalized P bf16 into sP = sKP, layout [q][k] stride PST ----
  unsigned short* sP = sKP;
#pragma unroll
  for (int kt = 0; kt < 6; ++kt) {
    ushort4 w = make_ushort4(f2bf(pv[kt][0]), f2bf(pv[kt][1]),
                             f2bf(pv[kt][2]), f2bf(pv[kt][3]));
    *reinterpret_cast<ushort4*>(&sP[(q0 + qc) * PST + kt * 16 + lgrp * 4]) = w;
  }

  // ---- phase 2: ctx^T = V^T @ P^T  (12 MFMA) ----
  bf16x8 pb[3];
#pragma unroll
  for (int ks = 0; ks < 3; ++ks)
    pb[ks] = *reinterpret_cast<const bf16x8*>(
        &sP[(q0 + qc) * PST + ks * 32 + lgrp * 8]);

  f32x4 ct[4] = {};
#pragma unroll
  for (int dt = 0; dt < 4; ++dt)
#pragma unroll
    for (int ks = 0; ks < 3; ++ks) {
      bf16x8 fa = *reinterpret_cast<const bf16x8*>(
          &sVT[(dt * 16 + qc) * PST + ks * 32 + lgrp * 8]);
      ct[dt] = __builtin_amdgcn_mfma_f32_16x16x32_bf16(fa, pb[ks], ct[dt], 0, 0, 0);
    }

  // ---- epilogue ----
  unsigned short* op =
      ctx + ((size_t)b * S_LEN + i0 + q0 + qc) * DMODEL + h * HD;
#pragma unroll
  for (int dt = 0; dt < 4; ++dt) {
    ushort4 w = make_ushort4(
        f2bf(ct[dt][0] * inv), f2bf(ct[dt][1] * inv),
        f2bf(ct[dt][2] * inv), f2bf(ct[dt][3] * inv));
    *reinterpret_cast<ushort4*>(op + dt * 16 + lgrp * 4) = w;
  }
}

// ---------------------------------------------------------------------------
extern "C" void kernel_launch(void* const* d_in, const int* in_sizes, int n_in,
                              void* d_out, int out_size, void* d_ws, size_t ws_size,
                              hipStream_t stream) {
  const float* x     = (const float*)d_in[0];
  const float* w_in  = (const float*)d_in[1];
  const float* b_in  = (const float*)d_in[2];
  const float* w_out = (const float*)d_in[3];
  const float* b_out = (const float*)d_in[4];
  float* out = (float*)d_out;

  // workspace layout (bf16 = ushort), total ~92 MB
  unsigned short* xb   = (unsigned short*)d_ws;
  unsigned short* wib  = xb  + (size_t)8192 * 1024;
  unsigned short* wob  = wib + (size_t)3072 * 1024;
  unsigned short* qkv  = wob + (size_t)1024 * 1024;
  unsigned short* ctxb = qkv + (size_t)8192 * 3072;

  cvt_bf16_kernel<<<8192, 256, 0, stream>>>(x, xb, (8192 * 1024) / 4);
  cvt_bf16_kernel<<<3072, 256, 0, stream>>>(w_in, wib, (3072 * 1024) / 4);
  cvt_bf16_kernel<<<1024, 256, 0, stream>>>(w_out, wob, (1024 * 1024) / 4);

  // QKV = x @ w_in^T + b_in -> [8192, 3072] bf16; 256x256 tiles, grid 32x12
  gemmdp_kernel<1, 2><<<384, 512, 0, stream>>>(
      xb, wib, b_in, (void*)qkv, 3072, 12);

  // windowed attention -> ctx [8192, 1024] bf16
  attn_local_kernel<<<BATCHN * NH * (S_LEN / 64), 256, 0, stream>>>(qkv, ctxb);

  // out = ctx @ w_out^T + b_out -> [8192, 1024] f32; 128x256 tiles, grid 64x4=256
  gemmdp_kernel<0, 1><<<256, 512, 0, stream>>>(
      ctxb, wob, b_out, (void*)out, 1024, 4);
}